// Round 1
// baseline (838.280 us; speedup 1.0000x reference)
//
#include <hip/hip_runtime.h>
#include <hip/hip_bf16.h>

#define BB 2
#define NN 4096
#define KNN 16
#define CC 64
#define CO 128
#define ROWS (BB*NN*KNN)   // 131072
#define K0 68              // 67 padded to 68
#define SW 132             // 128 padded to 132 (bank-conflict stride)

// ---------------- elementwise product P = features * neighbor_features ----------------
__global__ void k_prod(const float* __restrict__ f, const float* __restrict__ nf,
                       float* __restrict__ P) {
    int i = blockIdx.x * blockDim.x + threadIdx.x;
    int total = BB * NN * CC / 4;
    if (i < total) {
        float4 a = ((const float4*)f)[i];
        float4 b = ((const float4*)nf)[i];
        float4 r;
        r.x = __fmul_rn(a.x, b.x); r.y = __fmul_rn(a.y, b.y);
        r.z = __fmul_rn(a.z, b.z); r.w = __fmul_rn(a.w, b.w);
        ((float4*)P)[i] = r;
    }
}

// ---------------- ball query ----------------
__global__ __launch_bounds__(64) void k_ball(const float* __restrict__ anchor,
                                             const float* __restrict__ neighbor,
                                             int* __restrict__ idx) {
    __shared__ float nb[NN * 3];
    __shared__ int sres[64 * 17];
    int b = blockIdx.x >> 6;
    int tile = blockIdx.x & 63;
    const float* nbG = neighbor + b * NN * 3;
    for (int i = threadIdx.x; i < NN * 3 / 4; i += 64)
        ((float4*)nb)[i] = ((const float4*)nbG)[i];
    __syncthreads();

    int n = tile * 64 + threadIdx.x;
    int an = b * NN + n;
    float ax = anchor[an * 3 + 0];
    float ay = anchor[an * 3 + 1];
    float az = anchor[an * 3 + 2];

    int cnt = 0;
    int* myres = &sres[threadIdx.x * 17];
    for (int j = 0; j < NN && cnt < KNN; ++j) {
        float dx = __fsub_rn(ax, nb[j * 3 + 0]);
        float dy = __fsub_rn(ay, nb[j * 3 + 1]);
        float dz = __fsub_rn(az, nb[j * 3 + 2]);
        float d2 = __fadd_rn(__fadd_rn(__fmul_rn(dx, dx), __fmul_rn(dy, dy)),
                             __fmul_rn(dz, dz));
        if (d2 < 1.0f) { myres[cnt++] = j; }
    }
    int first = (cnt > 0) ? myres[0] : 0;
    int* out = idx + an * KNN;
    for (int t = 0; t < KNN; ++t) out[t] = (t < cnt) ? myres[t] : first;
}

// ---------------- GEMM0: gather + [dxyz, P] @ W0^T, relu, stats ----------------
__global__ __launch_bounds__(256) void k_gemm0(const float* __restrict__ anchor,
                                               const float* __restrict__ neighbor,
                                               const float* __restrict__ P,
                                               const int* __restrict__ idx,
                                               const float* __restrict__ W0,
                                               float* __restrict__ y0,
                                               float* __restrict__ stats) {
    __shared__ float Xs[128 * K0];
    __shared__ float Ws[128 * K0];
    __shared__ float sred[CO * 2];
    int t = threadIdx.x;
    int rowBase = blockIdx.x * 128;

    for (int i = t; i < CO * 2; i += 256) sred[i] = 0.0f;

    // W0 [128][67] -> Ws[o*68+k], pad col 67 = 0
    for (int i = t; i < 128 * K0; i += 256) {
        int o = i / K0, k = i - o * K0;
        Ws[i] = (k < 67) ? W0[o * 67 + k] : 0.0f;
    }
    // build X rows (2 threads per row)
    {
        int lr = t >> 1, h = t & 1;
        int r = rowBase + lr;
        int bn = r >> 4;           // b*4096+n
        int bb = bn >> 12;
        int j = idx[r];
        const float4* Prow = (const float4*)(P + ((bb << 12) + j) * CC);
        float* xrow = Xs + lr * K0;
#pragma unroll
        for (int q = 0; q < 8; ++q) {
            float4 v = Prow[h * 8 + q];
            int base = 3 + h * 32 + q * 4;
            xrow[base + 0] = v.x; xrow[base + 1] = v.y;
            xrow[base + 2] = v.z; xrow[base + 3] = v.w;
        }
        if (h == 0) {
            const float* nbr = neighbor + (bb * NN + j) * 3;
            xrow[0] = __fsub_rn(anchor[bn * 3 + 0], nbr[0]);
            xrow[1] = __fsub_rn(anchor[bn * 3 + 1], nbr[1]);
            xrow[2] = __fsub_rn(anchor[bn * 3 + 2], nbr[2]);
            xrow[67] = 0.0f;
        }
    }
    __syncthreads();

    int rt = t >> 4, ot = t & 15;
    float acc[8][8] = {};
    for (int kc = 0; kc < K0 / 4; ++kc) {
        float4 xq[8], wq[8];
#pragma unroll
        for (int i = 0; i < 8; ++i)
            xq[i] = *(const float4*)(Xs + (rt + 16 * i) * K0 + kc * 4);
#pragma unroll
        for (int jj = 0; jj < 8; ++jj)
            wq[jj] = *(const float4*)(Ws + (ot + 16 * jj) * K0 + kc * 4);
#pragma unroll
        for (int i = 0; i < 8; ++i)
#pragma unroll
            for (int jj = 0; jj < 8; ++jj) {
                acc[i][jj] = fmaf(xq[i].x, wq[jj].x, acc[i][jj]);
                acc[i][jj] = fmaf(xq[i].y, wq[jj].y, acc[i][jj]);
                acc[i][jj] = fmaf(xq[i].z, wq[jj].z, acc[i][jj]);
                acc[i][jj] = fmaf(xq[i].w, wq[jj].w, acc[i][jj]);
            }
    }

    // relu, store y0, per-channel partial stats
#pragma unroll
    for (int jj = 0; jj < 8; ++jj) {
        int o = ot + 16 * jj;
        float psum = 0.0f, psq = 0.0f;
#pragma unroll
        for (int i = 0; i < 8; ++i) {
            float v = fmaxf(acc[i][jj], 0.0f);
            y0[(rowBase + rt + 16 * i) * CO + o] = v;
            psum += v; psq += v * v;
        }
        atomicAdd(&sred[o * 2 + 0], psum);
        atomicAdd(&sred[o * 2 + 1], psq);
    }
    __syncthreads();
    int slot = blockIdx.x & 15;
    for (int i = t; i < CO * 2; i += 256)
        atomicAdd(&stats[slot * CO * 2 + i], sred[i]);
}

// ---------------- GEMM 1/2: x = transform(Xin) @ W^T, store raw, stats ----------------
// MODE 1: x = v*scale+shift   (layer1 input = BN0(relu h0))
// MODE 2: x = relu(v*scale+shift)  (layer2 input = relu(BN1(h1)))
template<int MODE>
__global__ __launch_bounds__(256) void k_gemm12(const float* __restrict__ Xin,
                                                const float* __restrict__ W,
                                                const float* __restrict__ bnp,
                                                float* __restrict__ Hout,
                                                float* __restrict__ stats) {
    __shared__ float Xs[128 * SW];
    __shared__ float Ws[128 * SW];
    __shared__ float sred[CO * 2];
    __shared__ float sbn[CO * 2];
    int t = threadIdx.x;
    int rowBase = blockIdx.x * 128;

    sbn[t] = bnp[t];                       // 256 == CO*2
    for (int i = t; i < CO * 2; i += 256) sred[i] = 0.0f;
    __syncthreads();

    // W [128][128] -> Ws (stride SW)
    for (int i = t; i < 128 * 128 / 4; i += 256) {
        int o = i >> 5, kq = i & 31;
        float4 v = ((const float4*)W)[i];
        *(float4*)(Ws + o * SW + kq * 4) = v;
    }
    // X tile with per-channel transform
    for (int i = t; i < 128 * 128 / 4; i += 256) {
        int lr = i >> 5, kq = i & 31;
        float4 v = ((const float4*)(Xin + (size_t)(rowBase + lr) * CO))[kq];
        int c = kq * 4;
        float4 r;
        r.x = v.x * sbn[(c + 0) * 2] + sbn[(c + 0) * 2 + 1];
        r.y = v.y * sbn[(c + 1) * 2] + sbn[(c + 1) * 2 + 1];
        r.z = v.z * sbn[(c + 2) * 2] + sbn[(c + 2) * 2 + 1];
        r.w = v.w * sbn[(c + 3) * 2] + sbn[(c + 3) * 2 + 1];
        if (MODE == 2) {
            r.x = fmaxf(r.x, 0.0f); r.y = fmaxf(r.y, 0.0f);
            r.z = fmaxf(r.z, 0.0f); r.w = fmaxf(r.w, 0.0f);
        }
        *(float4*)(Xs + lr * SW + kq * 4) = r;
    }
    __syncthreads();

    int rt = t >> 4, ot = t & 15;
    float acc[8][8] = {};
    for (int kc = 0; kc < 32; ++kc) {
        float4 xq[8], wq[8];
#pragma unroll
        for (int i = 0; i < 8; ++i)
            xq[i] = *(const float4*)(Xs + (rt + 16 * i) * SW + kc * 4);
#pragma unroll
        for (int jj = 0; jj < 8; ++jj)
            wq[jj] = *(const float4*)(Ws + (ot + 16 * jj) * SW + kc * 4);
#pragma unroll
        for (int i = 0; i < 8; ++i)
#pragma unroll
            for (int jj = 0; jj < 8; ++jj) {
                acc[i][jj] = fmaf(xq[i].x, wq[jj].x, acc[i][jj]);
                acc[i][jj] = fmaf(xq[i].y, wq[jj].y, acc[i][jj]);
                acc[i][jj] = fmaf(xq[i].z, wq[jj].z, acc[i][jj]);
                acc[i][jj] = fmaf(xq[i].w, wq[jj].w, acc[i][jj]);
            }
    }

    // store raw pre-BN output + stats on raw values
#pragma unroll
    for (int jj = 0; jj < 8; ++jj) {
        int o = ot + 16 * jj;
        float psum = 0.0f, psq = 0.0f;
#pragma unroll
        for (int i = 0; i < 8; ++i) {
            float v = acc[i][jj];
            Hout[(size_t)(rowBase + rt + 16 * i) * CO + o] = v;
            psum += v; psq += v * v;
        }
        atomicAdd(&sred[o * 2 + 0], psum);
        atomicAdd(&sred[o * 2 + 1], psq);
    }
    __syncthreads();
    int slot = blockIdx.x & 15;
    for (int i = t; i < CO * 2; i += 256)
        atomicAdd(&stats[slot * CO * 2 + i], sred[i]);
}

// ---------------- BN finalize: scale/shift per channel ----------------
__global__ void k_bnfin(const float* __restrict__ stats, const float* __restrict__ gamma,
                        const float* __restrict__ beta, float* __restrict__ bnp) {
    int o = threadIdx.x;  // 128
    float S = 0.0f, Q = 0.0f;
    for (int s = 0; s < 16; ++s) {
        S += stats[s * CO * 2 + o * 2 + 0];
        Q += stats[s * CO * 2 + o * 2 + 1];
    }
    float inv = 1.0f / (float)ROWS;
    float mean = S * inv;
    float var = Q * inv - mean * mean;
    float sc = gamma[o] * rsqrtf(var + 1e-5f);
    bnp[o * 2 + 0] = sc;
    bnp[o * 2 + 1] = beta[o] - mean * sc;
}

// ---------------- output: max over K of relu(BN2(h2)) ----------------
__global__ __launch_bounds__(256) void k_out(const float* __restrict__ h2,
                                             const float* __restrict__ bnp,
                                             float* __restrict__ out) {
    int i = blockIdx.x * 256 + threadIdx.x;   // over B*N*CO
    int o = i & 127;
    int bn = i >> 7;
    float sc = bnp[o * 2 + 0], sh = bnp[o * 2 + 1];
    const float* hrow = h2 + (size_t)bn * KNN * CO + o;
    float m = 0.0f;  // relu floor
#pragma unroll
    for (int k = 0; k < KNN; ++k) {
        float v = hrow[k * CO] * sc + sh;
        m = fmaxf(m, v);
    }
    out[i] = m;
}

extern "C" void kernel_launch(void* const* d_in, const int* in_sizes, int n_in,
                              void* d_out, int out_size, void* d_ws, size_t ws_size,
                              hipStream_t stream) {
    (void)in_sizes; (void)n_in; (void)out_size; (void)ws_size;
    const float* anchor = (const float*)d_in[0];
    const float* neighbor = (const float*)d_in[1];
    const float* nfeat = (const float*)d_in[2];
    const float* feat = (const float*)d_in[3];
    const float* W0 = (const float*)d_in[4];
    const float* g0 = (const float*)d_in[5];
    const float* b0 = (const float*)d_in[6];
    const float* W1 = (const float*)d_in[7];
    const float* g1 = (const float*)d_in[8];
    const float* b1 = (const float*)d_in[9];
    const float* W2 = (const float*)d_in[10];
    const float* g2 = (const float*)d_in[11];
    const float* b2 = (const float*)d_in[12];
    float* out = (float*)d_out;

    char* ws = (char*)d_ws;
    size_t o_idx = 0;                                  // 131072 * 4
    size_t o_P = o_idx + (size_t)ROWS * 4;             // 2MB
    size_t o_stats = o_P + (size_t)BB * NN * CC * 4;   // 3 * 16*CO*2*4 = 49152
    size_t o_bnp = o_stats + 3 * 16 * CO * 2 * 4;      // 3 * CO*2*4 = 3072
    size_t o_bufA = (o_bnp + 3 * CO * 2 * 4 + 255) & ~(size_t)255;
    size_t o_bufB = o_bufA + (size_t)ROWS * CO * 4;

    int* idx = (int*)(ws + o_idx);
    float* P = (float*)(ws + o_P);
    float* stats0 = (float*)(ws + o_stats);
    float* stats1 = stats0 + 16 * CO * 2;
    float* stats2 = stats1 + 16 * CO * 2;
    float* bnp0 = (float*)(ws + o_bnp);
    float* bnp1 = bnp0 + CO * 2;
    float* bnp2 = bnp1 + CO * 2;
    float* bufA = (float*)(ws + o_bufA);   // y0, later h2
    float* bufB = (float*)(ws + o_bufB);   // h1

    hipMemsetAsync(ws + o_stats, 0, 3 * 16 * CO * 2 * 4, stream);

    k_prod<<<BB * NN * CC / 4 / 256, 256, 0, stream>>>(feat, nfeat, P);
    k_ball<<<BB * (NN / 64), 64, 0, stream>>>(anchor, neighbor, idx);
    k_gemm0<<<ROWS / 128, 256, 0, stream>>>(anchor, neighbor, P, idx, W0, bufA, stats0);
    k_bnfin<<<1, CO, 0, stream>>>(stats0, g0, b0, bnp0);
    k_gemm12<1><<<ROWS / 128, 256, 0, stream>>>(bufA, W1, bnp0, bufB, stats1);
    k_bnfin<<<1, CO, 0, stream>>>(stats1, g1, b1, bnp1);
    k_gemm12<2><<<ROWS / 128, 256, 0, stream>>>(bufB, W2, bnp1, bufA, stats2);
    k_bnfin<<<1, CO, 0, stream>>>(stats2, g2, b2, bnp2);
    k_out<<<BB * NN * CO / 256, 256, 0, stream>>>(bufA, bnp2, out);
}

// Round 2
// 326.486 us; speedup vs baseline: 2.5676x; 2.5676x over previous
//
#include <hip/hip_runtime.h>
#include <hip/hip_bf16.h>

#define BB 2
#define NN 4096
#define KNN 16
#define CC 64
#define CO 128
#define ROWS (BB*NN*KNN)   // 131072
#define K0 68              // 67 padded to 68
#define SW 132             // 128 padded to 132 (bank-conflict stride)

// ---------------- elementwise product P = features * neighbor_features ----------------
__global__ void k_prod(const float* __restrict__ f, const float* __restrict__ nf,
                       float* __restrict__ P) {
    int i = blockIdx.x * blockDim.x + threadIdx.x;
    int total = BB * NN * CC / 4;
    if (i < total) {
        float4 a = ((const float4*)f)[i];
        float4 b = ((const float4*)nf)[i];
        float4 r;
        r.x = __fmul_rn(a.x, b.x); r.y = __fmul_rn(a.y, b.y);
        r.z = __fmul_rn(a.z, b.z); r.w = __fmul_rn(a.w, b.w);
        ((float4*)P)[i] = r;
    }
}

// ---------------- ball query: one anchor per wave, ballot-based ordered extraction ----------------
__global__ __launch_bounds__(256) void k_ball(const float* __restrict__ anchor,
                                              const float* __restrict__ neighbor,
                                              int* __restrict__ idx) {
    int lane = threadIdx.x & 63;
    int an = blockIdx.x * 4 + (threadIdx.x >> 6);   // 0..8191
    int b = an >> 12;
    const float* nb = neighbor + (size_t)b * NN * 3;

    float ax = anchor[an * 3 + 0];
    float ay = anchor[an * 3 + 1];
    float az = anchor[an * 3 + 2];

    unsigned long long lmask = (lane == 63) ? 0xFFFFFFFFFFFFFFFFull >> 1
                                            : ((1ull << lane) - 1ull);
    int cnt = 0;
    int firstIdx = -1;
    int* myout = idx + (size_t)an * KNN;

    for (int chunk = 0; chunk < NN / 64 && cnt < KNN; ++chunk) {
        int j = chunk * 64 + lane;
        float dx = __fsub_rn(ax, nb[j * 3 + 0]);
        float dy = __fsub_rn(ay, nb[j * 3 + 1]);
        float dz = __fsub_rn(az, nb[j * 3 + 2]);
        float d2 = __fadd_rn(__fadd_rn(__fmul_rn(dx, dx), __fmul_rn(dy, dy)),
                             __fmul_rn(dz, dz));
        bool hit = d2 < 1.0f;
        unsigned long long m = __ballot(hit);
        if (m) {
            int pos = cnt + __popcll(m & lmask);
            if (hit && pos < KNN) myout[pos] = j;
            if (firstIdx < 0) firstIdx = chunk * 64 + (__ffsll((long long)m) - 1);
            cnt += __popcll(m);
        }
    }
    if (cnt < KNN) {
        int f = (firstIdx < 0) ? 0 : firstIdx;
        if (lane >= cnt && lane < KNN) myout[lane] = f;
    }
}

// ---------------- GEMM0: gather + [dxyz, P] @ W0^T, relu, stats ----------------
__global__ __launch_bounds__(256) void k_gemm0(const float* __restrict__ anchor,
                                               const float* __restrict__ neighbor,
                                               const float* __restrict__ P,
                                               const int* __restrict__ idx,
                                               const float* __restrict__ W0,
                                               float* __restrict__ y0,
                                               float* __restrict__ stats) {
    __shared__ float Xs[128 * K0];
    __shared__ float Ws[128 * K0];
    __shared__ float sred[CO * 2];
    int t = threadIdx.x;
    int rowBase = blockIdx.x * 128;

    for (int i = t; i < CO * 2; i += 256) sred[i] = 0.0f;

    // W0 [128][67] -> Ws[o*68+k], pad col 67 = 0
    for (int i = t; i < 128 * K0; i += 256) {
        int o = i / K0, k = i - o * K0;
        Ws[i] = (k < 67) ? W0[o * 67 + k] : 0.0f;
    }
    // build X rows (2 threads per row)
    {
        int lr = t >> 1, h = t & 1;
        int r = rowBase + lr;
        int bn = r >> 4;           // b*4096+n
        int bb = bn >> 12;
        int j = idx[r];
        const float4* Prow = (const float4*)(P + ((bb << 12) + j) * CC);
        float* xrow = Xs + lr * K0;
#pragma unroll
        for (int q = 0; q < 8; ++q) {
            float4 v = Prow[h * 8 + q];
            int base = 3 + h * 32 + q * 4;
            xrow[base + 0] = v.x; xrow[base + 1] = v.y;
            xrow[base + 2] = v.z; xrow[base + 3] = v.w;
        }
        if (h == 0) {
            const float* nbr = neighbor + (bb * NN + j) * 3;
            xrow[0] = __fsub_rn(anchor[bn * 3 + 0], nbr[0]);
            xrow[1] = __fsub_rn(anchor[bn * 3 + 1], nbr[1]);
            xrow[2] = __fsub_rn(anchor[bn * 3 + 2], nbr[2]);
            xrow[67] = 0.0f;
        }
    }
    __syncthreads();

    int rt = t >> 4, ot = t & 15;
    float acc[8][8] = {};
    for (int kc = 0; kc < K0 / 4; ++kc) {
        float4 xq[8], wq[8];
#pragma unroll
        for (int i = 0; i < 8; ++i)
            xq[i] = *(const float4*)(Xs + (rt + 16 * i) * K0 + kc * 4);
#pragma unroll
        for (int jj = 0; jj < 8; ++jj)
            wq[jj] = *(const float4*)(Ws + (ot + 16 * jj) * K0 + kc * 4);
#pragma unroll
        for (int i = 0; i < 8; ++i)
#pragma unroll
            for (int jj = 0; jj < 8; ++jj) {
                acc[i][jj] = fmaf(xq[i].x, wq[jj].x, acc[i][jj]);
                acc[i][jj] = fmaf(xq[i].y, wq[jj].y, acc[i][jj]);
                acc[i][jj] = fmaf(xq[i].z, wq[jj].z, acc[i][jj]);
                acc[i][jj] = fmaf(xq[i].w, wq[jj].w, acc[i][jj]);
            }
    }

    // relu, store y0, per-channel partial stats
#pragma unroll
    for (int jj = 0; jj < 8; ++jj) {
        int o = ot + 16 * jj;
        float psum = 0.0f, psq = 0.0f;
#pragma unroll
        for (int i = 0; i < 8; ++i) {
            float v = fmaxf(acc[i][jj], 0.0f);
            y0[(rowBase + rt + 16 * i) * CO + o] = v;
            psum += v; psq += v * v;
        }
        atomicAdd(&sred[o * 2 + 0], psum);
        atomicAdd(&sred[o * 2 + 1], psq);
    }
    __syncthreads();
    int slot = blockIdx.x & 15;
    for (int i = t; i < CO * 2; i += 256)
        atomicAdd(&stats[slot * CO * 2 + i], sred[i]);
}

// ---------------- GEMM 1/2: x = transform(Xin) @ W^T, store raw, stats ----------------
// MODE 1: x = v*scale+shift   (layer1 input = BN0(relu h0))
// MODE 2: x = relu(v*scale+shift)  (layer2 input = relu(BN1(h1)))
template<int MODE>
__global__ __launch_bounds__(256) void k_gemm12(const float* __restrict__ Xin,
                                                const float* __restrict__ W,
                                                const float* __restrict__ bnp,
                                                float* __restrict__ Hout,
                                                float* __restrict__ stats) {
    __shared__ float Xs[128 * SW];
    __shared__ float Ws[128 * SW];
    __shared__ float sred[CO * 2];
    __shared__ float sbn[CO * 2];
    int t = threadIdx.x;
    int rowBase = blockIdx.x * 128;

    sbn[t] = bnp[t];                       // 256 == CO*2
    for (int i = t; i < CO * 2; i += 256) sred[i] = 0.0f;
    __syncthreads();

    // W [128][128] -> Ws (stride SW)
    for (int i = t; i < 128 * 128 / 4; i += 256) {
        int o = i >> 5, kq = i & 31;
        float4 v = ((const float4*)W)[i];
        *(float4*)(Ws + o * SW + kq * 4) = v;
    }
    // X tile with per-channel transform
    for (int i = t; i < 128 * 128 / 4; i += 256) {
        int lr = i >> 5, kq = i & 31;
        float4 v = ((const float4*)(Xin + (size_t)(rowBase + lr) * CO))[kq];
        int c = kq * 4;
        float4 r;
        r.x = v.x * sbn[(c + 0) * 2] + sbn[(c + 0) * 2 + 1];
        r.y = v.y * sbn[(c + 1) * 2] + sbn[(c + 1) * 2 + 1];
        r.z = v.z * sbn[(c + 2) * 2] + sbn[(c + 2) * 2 + 1];
        r.w = v.w * sbn[(c + 3) * 2] + sbn[(c + 3) * 2 + 1];
        if (MODE == 2) {
            r.x = fmaxf(r.x, 0.0f); r.y = fmaxf(r.y, 0.0f);
            r.z = fmaxf(r.z, 0.0f); r.w = fmaxf(r.w, 0.0f);
        }
        *(float4*)(Xs + lr * SW + kq * 4) = r;
    }
    __syncthreads();

    int rt = t >> 4, ot = t & 15;
    float acc[8][8] = {};
    for (int kc = 0; kc < 32; ++kc) {
        float4 xq[8], wq[8];
#pragma unroll
        for (int i = 0; i < 8; ++i)
            xq[i] = *(const float4*)(Xs + (rt + 16 * i) * SW + kc * 4);
#pragma unroll
        for (int jj = 0; jj < 8; ++jj)
            wq[jj] = *(const float4*)(Ws + (ot + 16 * jj) * SW + kc * 4);
#pragma unroll
        for (int i = 0; i < 8; ++i)
#pragma unroll
            for (int jj = 0; jj < 8; ++jj) {
                acc[i][jj] = fmaf(xq[i].x, wq[jj].x, acc[i][jj]);
                acc[i][jj] = fmaf(xq[i].y, wq[jj].y, acc[i][jj]);
                acc[i][jj] = fmaf(xq[i].z, wq[jj].z, acc[i][jj]);
                acc[i][jj] = fmaf(xq[i].w, wq[jj].w, acc[i][jj]);
            }
    }

    // store raw pre-BN output + stats on raw values
#pragma unroll
    for (int jj = 0; jj < 8; ++jj) {
        int o = ot + 16 * jj;
        float psum = 0.0f, psq = 0.0f;
#pragma unroll
        for (int i = 0; i < 8; ++i) {
            float v = acc[i][jj];
            Hout[(size_t)(rowBase + rt + 16 * i) * CO + o] = v;
            psum += v; psq += v * v;
        }
        atomicAdd(&sred[o * 2 + 0], psum);
        atomicAdd(&sred[o * 2 + 1], psq);
    }
    __syncthreads();
    int slot = blockIdx.x & 15;
    for (int i = t; i < CO * 2; i += 256)
        atomicAdd(&stats[slot * CO * 2 + i], sred[i]);
}

// ---------------- BN finalize: scale/shift per channel ----------------
__global__ void k_bnfin(const float* __restrict__ stats, const float* __restrict__ gamma,
                        const float* __restrict__ beta, float* __restrict__ bnp) {
    int o = threadIdx.x;  // 128
    float S = 0.0f, Q = 0.0f;
    for (int s = 0; s < 16; ++s) {
        S += stats[s * CO * 2 + o * 2 + 0];
        Q += stats[s * CO * 2 + o * 2 + 1];
    }
    float inv = 1.0f / (float)ROWS;
    float mean = S * inv;
    float var = Q * inv - mean * mean;
    float sc = gamma[o] * rsqrtf(var + 1e-5f);
    bnp[o * 2 + 0] = sc;
    bnp[o * 2 + 1] = beta[o] - mean * sc;
}

// ---------------- output: max over K of relu(BN2(h2)) ----------------
__global__ __launch_bounds__(256) void k_out(const float* __restrict__ h2,
                                             const float* __restrict__ bnp,
                                             float* __restrict__ out) {
    int i = blockIdx.x * 256 + threadIdx.x;   // over B*N*CO
    int o = i & 127;
    int bn = i >> 7;
    float sc = bnp[o * 2 + 0], sh = bnp[o * 2 + 1];
    const float* hrow = h2 + (size_t)bn * KNN * CO + o;
    float m = 0.0f;  // relu floor
#pragma unroll
    for (int k = 0; k < KNN; ++k) {
        float v = hrow[k * CO] * sc + sh;
        m = fmaxf(m, v);
    }
    out[i] = m;
}

extern "C" void kernel_launch(void* const* d_in, const int* in_sizes, int n_in,
                              void* d_out, int out_size, void* d_ws, size_t ws_size,
                              hipStream_t stream) {
    (void)in_sizes; (void)n_in; (void)out_size; (void)ws_size;
    const float* anchor = (const float*)d_in[0];
    const float* neighbor = (const float*)d_in[1];
    const float* nfeat = (const float*)d_in[2];
    const float* feat = (const float*)d_in[3];
    const float* W0 = (const float*)d_in[4];
    const float* g0 = (const float*)d_in[5];
    const float* b0 = (const float*)d_in[6];
    const float* W1 = (const float*)d_in[7];
    const float* g1 = (const float*)d_in[8];
    const float* b1 = (const float*)d_in[9];
    const float* W2 = (const float*)d_in[10];
    const float* g2 = (const float*)d_in[11];
    const float* b2 = (const float*)d_in[12];
    float* out = (float*)d_out;

    char* ws = (char*)d_ws;
    size_t o_idx = 0;                                  // 131072 * 4
    size_t o_P = o_idx + (size_t)ROWS * 4;             // 2MB
    size_t o_stats = o_P + (size_t)BB * NN * CC * 4;   // 3 * 16*CO*2*4 = 49152
    size_t o_bnp = o_stats + 3 * 16 * CO * 2 * 4;      // 3 * CO*2*4 = 3072
    size_t o_bufA = (o_bnp + 3 * CO * 2 * 4 + 255) & ~(size_t)255;
    size_t o_bufB = o_bufA + (size_t)ROWS * CO * 4;

    int* idx = (int*)(ws + o_idx);
    float* P = (float*)(ws + o_P);
    float* stats0 = (float*)(ws + o_stats);
    float* stats1 = stats0 + 16 * CO * 2;
    float* stats2 = stats1 + 16 * CO * 2;
    float* bnp0 = (float*)(ws + o_bnp);
    float* bnp1 = bnp0 + CO * 2;
    float* bnp2 = bnp1 + CO * 2;
    float* bufA = (float*)(ws + o_bufA);   // y0, later h2
    float* bufB = (float*)(ws + o_bufB);   // h1

    hipMemsetAsync(ws + o_stats, 0, 3 * 16 * CO * 2 * 4, stream);

    k_prod<<<BB * NN * CC / 4 / 256, 256, 0, stream>>>(feat, nfeat, P);
    k_ball<<<BB * NN / 4, 256, 0, stream>>>(anchor, neighbor, idx);
    k_gemm0<<<ROWS / 128, 256, 0, stream>>>(anchor, neighbor, P, idx, W0, bufA, stats0);
    k_bnfin<<<1, CO, 0, stream>>>(stats0, g0, b0, bnp0);
    k_gemm12<1><<<ROWS / 128, 256, 0, stream>>>(bufA, W1, bnp0, bufB, stats1);
    k_bnfin<<<1, CO, 0, stream>>>(stats1, g1, b1, bnp1);
    k_gemm12<2><<<ROWS / 128, 256, 0, stream>>>(bufB, W2, bnp1, bufA, stats2);
    k_bnfin<<<1, CO, 0, stream>>>(stats2, g2, b2, bnp2);
    k_out<<<BB * NN * CO / 256, 256, 0, stream>>>(bufA, bnp2, out);
}

// Round 5
// 144.707 us; speedup vs baseline: 5.7929x; 2.2562x over previous
//
#include <hip/hip_runtime.h>
#include <hip/hip_bf16.h>

#define BB 2
#define NN 4096
#define KNN 16
#define CC 64
#define CO 128
#define ROWS (BB*NN*KNN)   // 131072

typedef __attribute__((ext_vector_type(8))) short bf16x8;
typedef __attribute__((ext_vector_type(4))) float f32x4;

__device__ __forceinline__ float bf2f(unsigned short u) {
    return __uint_as_float(((unsigned)u) << 16);
}
__device__ __forceinline__ unsigned short f2bf(float f) {
    __hip_bfloat16 h = __float2bfloat16(f);
    return *reinterpret_cast<unsigned short*>(&h);
}

union U16B { uint4 v; unsigned short us[8]; };

// ---------------- P = features * neighbor_features  (bf16 out) ----------------
__global__ void k_prod(const float* __restrict__ f, const float* __restrict__ nf,
                       unsigned short* __restrict__ P) {
    int i = blockIdx.x * blockDim.x + threadIdx.x;
    int total = BB * NN * CC / 4;
    if (i < total) {
        float4 a = ((const float4*)f)[i];
        float4 b = ((const float4*)nf)[i];
        ushort4 r;
        r.x = f2bf(__fmul_rn(a.x, b.x));
        r.y = f2bf(__fmul_rn(a.y, b.y));
        r.z = f2bf(__fmul_rn(a.z, b.z));
        r.w = f2bf(__fmul_rn(a.w, b.w));
        ((ushort4*)P)[i] = r;
    }
}

// ---------------- ball query: one anchor per wave, ballot ordered extraction ----------------
__global__ __launch_bounds__(256) void k_ball(const float* __restrict__ anchor,
                                              const float* __restrict__ neighbor,
                                              int* __restrict__ idx) {
    int lane = threadIdx.x & 63;
    int an = blockIdx.x * 4 + (threadIdx.x >> 6);   // 0..8191
    int b = an >> 12;
    const float* nb = neighbor + (size_t)b * NN * 3;

    float ax = anchor[an * 3 + 0];
    float ay = anchor[an * 3 + 1];
    float az = anchor[an * 3 + 2];

    unsigned long long lmask = (lane == 63) ? 0xFFFFFFFFFFFFFFFFull >> 1
                                            : ((1ull << lane) - 1ull);
    int cnt = 0;
    int firstIdx = -1;
    int* myout = idx + (size_t)an * KNN;

    for (int chunk = 0; chunk < NN / 64 && cnt < KNN; ++chunk) {
        int j = chunk * 64 + lane;
        float dx = __fsub_rn(ax, nb[j * 3 + 0]);
        float dy = __fsub_rn(ay, nb[j * 3 + 1]);
        float dz = __fsub_rn(az, nb[j * 3 + 2]);
        float d2 = __fadd_rn(__fadd_rn(__fmul_rn(dx, dx), __fmul_rn(dy, dy)),
                             __fmul_rn(dz, dz));
        bool hit = d2 < 1.0f;
        unsigned long long m = __ballot(hit);
        if (m) {
            int pos = cnt + __popcll(m & lmask);
            if (hit && pos < KNN) myout[pos] = j;
            if (firstIdx < 0) firstIdx = chunk * 64 + (__ffsll((long long)m) - 1);
            cnt += __popcll(m);
        }
    }
    if (cnt < KNN) {
        int f = (firstIdx < 0) ? 0 : firstIdx;
        if (lane >= cnt && lane < KNN) myout[lane] = f;
    }
}

// ======================= GEMM0 (MFMA): gather + X@W0^T, relu, stats =======================
// X K-layout (permuted): k 0..63 = P (prod features), k 64..66 = dxyz, k 67..95 = 0
// W0 columns permuted to match. K = 96 (3 chunks of 32).
#define K0P 96
#define XST 104   // 96 + 8 pad (bf16 elems); row stride 208 B, 16B aligned
__global__ __launch_bounds__(256) void k_gemm0(const float* __restrict__ anchor,
                                               const float* __restrict__ neighbor,
                                               const unsigned short* __restrict__ P,
                                               const int* __restrict__ idx,
                                               const float* __restrict__ W0,
                                               unsigned short* __restrict__ y0,
                                               float* __restrict__ stats) {
    __shared__ alignas(16) short Xs[128 * XST];
    __shared__ alignas(16) short Ws[128 * XST];
    __shared__ float sred[CO * 2];
    int t = threadIdx.x;
    int rowBase = blockIdx.x * 128;

    for (int i = t; i < CO * 2; i += 256) sred[i] = 0.0f;

    // stage W0 with column permutation -> bf16
    for (int i = t; i < 128 * K0P; i += 256) {
        int o = i / K0P, k = i - o * K0P;
        float v;
        if (k < 64)      v = W0[o * 67 + 3 + k];
        else if (k < 67) v = W0[o * 67 + (k - 64)];
        else             v = 0.0f;
        Ws[o * XST + k] = (short)f2bf(v);
    }
    // build X tile: 2 threads per row
    {
        int lr = t >> 1, h = t & 1;
        int r = rowBase + lr;
        int bn = r >> 4;           // b*4096+n
        int bb = bn >> 12;
        int j = idx[r];
        const uint4* Prow = (const uint4*)(P + (size_t)((bb << 12) + j) * CC);
#pragma unroll
        for (int q = 0; q < 4; ++q)
            *(uint4*)&Xs[lr * XST + (h * 4 + q) * 8] = Prow[h * 4 + q];
        if (h == 1) {
            const float* nbr = neighbor + (size_t)((bb << 12) + j) * 3;
            float dx = __fsub_rn(anchor[bn * 3 + 0], nbr[0]);
            float dy = __fsub_rn(anchor[bn * 3 + 1], nbr[1]);
            float dz = __fsub_rn(anchor[bn * 3 + 2], nbr[2]);
            uint4 t0;
            t0.x = (unsigned)f2bf(dx) | ((unsigned)f2bf(dy) << 16);
            t0.y = (unsigned)f2bf(dz);
            t0.z = 0u; t0.w = 0u;
            *(uint4*)&Xs[lr * XST + 64] = t0;
            uint4 z; z.x = z.y = z.z = z.w = 0u;
            *(uint4*)&Xs[lr * XST + 72] = z;
            *(uint4*)&Xs[lr * XST + 80] = z;
            *(uint4*)&Xs[lr * XST + 88] = z;
        }
    }
    __syncthreads();

    int lane = t & 63, w = t >> 6;
    int lm = lane & 15, g = lane >> 4;
    f32x4 zero = {0.f, 0.f, 0.f, 0.f};
    f32x4 acc[2][8];
#pragma unroll
    for (int i = 0; i < 2; ++i)
#pragma unroll
        for (int c = 0; c < 8; ++c) acc[i][c] = zero;

#pragma unroll
    for (int kc = 0; kc < 3; ++kc) {
        int koff = kc * 32 + g * 8;
        bf16x8 afr[2];
#pragma unroll
        for (int i = 0; i < 2; ++i)
            afr[i] = *(const bf16x8*)&Xs[(w * 32 + i * 16 + lm) * XST + koff];
#pragma unroll
        for (int ct = 0; ct < 8; ++ct) {
            bf16x8 bfr = *(const bf16x8*)&Ws[(ct * 16 + lm) * XST + koff];
#pragma unroll
            for (int i = 0; i < 2; ++i)
                acc[i][ct] = __builtin_amdgcn_mfma_f32_16x16x32_bf16(afr[i], bfr, acc[i][ct], 0, 0, 0);
        }
    }

    // epilogue: relu, store bf16, stats (on relu'd values)
#pragma unroll
    for (int ct = 0; ct < 8; ++ct) {
        int o = lm + 16 * ct;
        float psum = 0.f, psq = 0.f;
#pragma unroll
        for (int i = 0; i < 2; ++i) {
#pragma unroll
            for (int rg = 0; rg < 4; ++rg) {
                float v = fmaxf(acc[i][ct][rg], 0.0f);
                int r = rowBase + w * 32 + i * 16 + g * 4 + rg;
                y0[(size_t)r * CO + o] = f2bf(v);
                psum += v; psq += v * v;
            }
        }
        psum += __shfl_xor(psum, 16); psq += __shfl_xor(psq, 16);
        psum += __shfl_xor(psum, 32); psq += __shfl_xor(psq, 32);
        if (lane < 16) {
            atomicAdd(&sred[o * 2 + 0], psum);
            atomicAdd(&sred[o * 2 + 1], psq);
        }
    }
    __syncthreads();
    int slot = blockIdx.x & 15;
    for (int i = t; i < CO * 2; i += 256)
        atomicAdd(&stats[slot * CO * 2 + i], sred[i]);
}

// ======================= GEMM 1/2 (MFMA) =======================
// A (rows of transformed X) loaded straight from global bf16; W staged in LDS bf16.
// MODE 1: x = v*sc+sh        MODE 2: x = relu(v*sc+sh)
#define WST 136   // 128 + 8 pad
template<int MODE>
__global__ __launch_bounds__(256) void k_gemm12(const unsigned short* __restrict__ Xin,
                                                const float* __restrict__ W,
                                                const float* __restrict__ bnp,
                                                unsigned short* __restrict__ Hout,
                                                float* __restrict__ stats) {
    __shared__ alignas(16) short Wl[128 * WST];
    __shared__ float ssc[CO];
    __shared__ float ssh[CO];
    __shared__ float sred[CO * 2];
    int t = threadIdx.x;
    int rowBase = blockIdx.x * 128;

    if (t < 128) ssc[t] = bnp[t];
    else         ssh[t - 128] = bnp[t];
    for (int i = t; i < CO * 2; i += 256) sred[i] = 0.0f;

    // stage W -> bf16 LDS
    for (int i = t; i < 128 * 32; i += 256) {
        int o = i >> 5, kq = i & 31;
        float4 v = ((const float4*)W)[i];
        ushort4 r;
        r.x = f2bf(v.x); r.y = f2bf(v.y); r.z = f2bf(v.z); r.w = f2bf(v.w);
        *(ushort4*)&Wl[o * WST + kq * 4] = r;
    }
    __syncthreads();

    int lane = t & 63, w = t >> 6;
    int lm = lane & 15, g = lane >> 4;
    f32x4 zero = {0.f, 0.f, 0.f, 0.f};
    f32x4 acc[2][8];
#pragma unroll
    for (int i = 0; i < 2; ++i)
#pragma unroll
        for (int c = 0; c < 8; ++c) acc[i][c] = zero;

#pragma unroll
    for (int kc = 0; kc < 4; ++kc) {
        int k0 = kc * 32 + g * 8;
        // BN params for this lane's k-slice (LDS broadcast within 16-lane group)
        float4 sc0 = *(const float4*)&ssc[k0];
        float4 sc1 = *(const float4*)&ssc[k0 + 4];
        float4 sh0 = *(const float4*)&ssh[k0];
        float4 sh1 = *(const float4*)&ssh[k0 + 4];
        float scv[8] = {sc0.x, sc0.y, sc0.z, sc0.w, sc1.x, sc1.y, sc1.z, sc1.w};
        float shv[8] = {sh0.x, sh0.y, sh0.z, sh0.w, sh1.x, sh1.y, sh1.z, sh1.w};

        bf16x8 afr[2];
#pragma unroll
        for (int i = 0; i < 2; ++i) {
            int r = rowBase + w * 32 + i * 16 + lm;
            U16B u;
            u.v = *(const uint4*)(Xin + (size_t)r * CO + k0);
#pragma unroll
            for (int j = 0; j < 8; ++j) {
                float v = bf2f(u.us[j]) * scv[j] + shv[j];
                if (MODE == 2) v = fmaxf(v, 0.0f);
                afr[i][j] = (short)f2bf(v);
            }
        }
#pragma unroll
        for (int ct = 0; ct < 8; ++ct) {
            bf16x8 bfr = *(const bf16x8*)&Wl[(ct * 16 + lm) * WST + k0];
#pragma unroll
            for (int i = 0; i < 2; ++i)
                acc[i][ct] = __builtin_amdgcn_mfma_f32_16x16x32_bf16(afr[i], bfr, acc[i][ct], 0, 0, 0);
        }
    }

    // epilogue: store raw bf16 + stats on raw values
#pragma unroll
    for (int ct = 0; ct < 8; ++ct) {
        int o = lm + 16 * ct;
        float psum = 0.f, psq = 0.f;
#pragma unroll
        for (int i = 0; i < 2; ++i) {
#pragma unroll
            for (int rg = 0; rg < 4; ++rg) {
                float v = acc[i][ct][rg];
                int r = rowBase + w * 32 + i * 16 + g * 4 + rg;
                Hout[(size_t)r * CO + o] = f2bf(v);
                psum += v; psq += v * v;
            }
        }
        psum += __shfl_xor(psum, 16); psq += __shfl_xor(psq, 16);
        psum += __shfl_xor(psum, 32); psq += __shfl_xor(psq, 32);
        if (lane < 16) {
            atomicAdd(&sred[o * 2 + 0], psum);
            atomicAdd(&sred[o * 2 + 1], psq);
        }
    }
    __syncthreads();
    int slot = blockIdx.x & 15;
    for (int i = t; i < CO * 2; i += 256)
        atomicAdd(&stats[slot * CO * 2 + i], sred[i]);
}

// ---------------- BN finalize: sc[128] then sh[128] ----------------
__global__ void k_bnfin(const float* __restrict__ stats, const float* __restrict__ gamma,
                        const float* __restrict__ beta, float* __restrict__ bnp) {
    int o = threadIdx.x;  // 128
    float S = 0.0f, Q = 0.0f;
    for (int s = 0; s < 16; ++s) {
        S += stats[s * CO * 2 + o * 2 + 0];
        Q += stats[s * CO * 2 + o * 2 + 1];
    }
    float inv = 1.0f / (float)ROWS;
    float mean = S * inv;
    float var = Q * inv - mean * mean;
    float sc = gamma[o] * rsqrtf(var + 1e-5f);
    bnp[o] = sc;
    bnp[o + 128] = beta[o] - mean * sc;
}

// ---------------- output: max over K of relu(BN2(h2)) ----------------
__global__ __launch_bounds__(256) void k_out(const unsigned short* __restrict__ h2,
                                             const float* __restrict__ bnp,
                                             float* __restrict__ out) {
    int i = blockIdx.x * 256 + threadIdx.x;   // over B*N*CO
    int o = i & 127;
    int bn = i >> 7;
    float sc = bnp[o], sh = bnp[o + 128];
    const unsigned short* hrow = h2 + (size_t)bn * KNN * CO + o;
    float m = 0.0f;  // relu floor
#pragma unroll
    for (int k = 0; k < KNN; ++k) {
        float v = bf2f(hrow[k * CO]) * sc + sh;
        m = fmaxf(m, v);
    }
    out[i] = m;
}

extern "C" void kernel_launch(void* const* d_in, const int* in_sizes, int n_in,
                              void* d_out, int out_size, void* d_ws, size_t ws_size,
                              hipStream_t stream) {
    (void)in_sizes; (void)n_in; (void)out_size; (void)ws_size;
    const float* anchor = (const float*)d_in[0];
    const float* neighbor = (const float*)d_in[1];
    const float* nfeat = (const float*)d_in[2];
    const float* feat = (const float*)d_in[3];
    const float* W0 = (const float*)d_in[4];
    const float* g0 = (const float*)d_in[5];
    const float* b0 = (const float*)d_in[6];
    const float* W1 = (const float*)d_in[7];
    const float* g1 = (const float*)d_in[8];
    const float* b1 = (const float*)d_in[9];
    const float* W2 = (const float*)d_in[10];
    const float* g2 = (const float*)d_in[11];
    const float* b2 = (const float*)d_in[12];
    float* out = (float*)d_out;

    char* ws = (char*)d_ws;
    size_t o_idx = 0;                                   // 512 KB
    size_t o_P = o_idx + (size_t)ROWS * 4;              // bf16 P: 1 MB
    size_t o_stats = o_P + (size_t)BB * NN * CC * 2;
    size_t o_bnp = o_stats + 3 * 16 * CO * 2 * 4;
    size_t o_bufA = (o_bnp + 3 * CO * 2 * 4 + 255) & ~(size_t)255;
    size_t o_bufB = o_bufA + (size_t)ROWS * CO * 2;     // bf16 buffers: 32 MB each

    int* idx = (int*)(ws + o_idx);
    unsigned short* P = (unsigned short*)(ws + o_P);
    float* stats0 = (float*)(ws + o_stats);
    float* stats1 = stats0 + 16 * CO * 2;
    float* stats2 = stats1 + 16 * CO * 2;
    float* bnp0 = (float*)(ws + o_bnp);
    float* bnp1 = bnp0 + CO * 2;
    float* bnp2 = bnp1 + CO * 2;
    unsigned short* bufA = (unsigned short*)(ws + o_bufA);   // y0, later h2
    unsigned short* bufB = (unsigned short*)(ws + o_bufB);   // h1

    hipMemsetAsync(ws + o_stats, 0, 3 * 16 * CO * 2 * 4, stream);

    k_prod<<<BB * NN * CC / 4 / 256, 256, 0, stream>>>(feat, nfeat, P);
    k_ball<<<BB * NN / 4, 256, 0, stream>>>(anchor, neighbor, idx);
    k_gemm0<<<ROWS / 128, 256, 0, stream>>>(anchor, neighbor, P, idx, W0, bufA, stats0);
    k_bnfin<<<1, CO, 0, stream>>>(stats0, g0, b0, bnp0);
    k_gemm12<1><<<ROWS / 128, 256, 0, stream>>>(bufA, W1, bnp0, bufB, stats1);
    k_bnfin<<<1, CO, 0, stream>>>(stats1, g1, b1, bnp1);
    k_gemm12<2><<<ROWS / 128, 256, 0, stream>>>(bufB, W2, bnp1, bufA, stats2);
    k_bnfin<<<1, CO, 0, stream>>>(stats2, g2, b2, bnp2);
    k_out<<<BB * NN * CO / 256, 256, 0, stream>>>(bufA, bnp2, out);
}

// Round 7
// 122.354 us; speedup vs baseline: 6.8513x; 1.1827x over previous
//
#include <hip/hip_runtime.h>
#include <hip/hip_bf16.h>

#define BB 2
#define NN 4096
#define KNN 16
#define CC 64
#define CO 128
#define ROWS (BB*NN*KNN)   // 131072
#define K0P 96             // padded/permuted K for layer 0

typedef __attribute__((ext_vector_type(8))) short bf16x8;
typedef __attribute__((ext_vector_type(4))) float f32x4;

__device__ __forceinline__ float bf2f(unsigned short u) {
    return __uint_as_float(((unsigned)u) << 16);
}
__device__ __forceinline__ unsigned short f2bf(float f) {
    __hip_bfloat16 h = __float2bfloat16(f);
    return *reinterpret_cast<unsigned short*>(&h);
}

union U16B { uint4 v; unsigned short us[8]; };

// ---------------- weight prep: W0 col-permuted+padded, W1/W2 converted, all bf16 ----------------
// W0p[o][k]: k 0..63 = W0[o][3+k], k 64..66 = W0[o][k-64], k 67..95 = 0.  (matches X layout)
__global__ void k_prep(const float* __restrict__ W0, const float* __restrict__ W1,
                       const float* __restrict__ W2,
                       short* __restrict__ W0p, short* __restrict__ W12p) {
    int i = blockIdx.x * 256 + threadIdx.x;
    if (i < 128 * K0P) {
        int o = i / K0P, k = i - o * K0P;
        float v;
        if (k < 64)      v = W0[o * 67 + 3 + k];
        else if (k < 67) v = W0[o * 67 + (k - 64)];
        else             v = 0.0f;
        W0p[i] = (short)f2bf(v);
    } else if (i < 128 * K0P + 16384) {
        int e = i - 128 * K0P;
        W12p[e] = (short)f2bf(W1[e]);
    } else if (i < 128 * K0P + 32768) {
        int e = i - 128 * K0P - 16384;
        W12p[16384 + e] = (short)f2bf(W2[e]);
    }
}

// ---------------- P = features * neighbor_features  (bf16 out) ----------------
__global__ void k_prod(const float* __restrict__ f, const float* __restrict__ nf,
                       unsigned short* __restrict__ P) {
    int i = blockIdx.x * blockDim.x + threadIdx.x;
    int total = BB * NN * CC / 4;
    if (i < total) {
        float4 a = ((const float4*)f)[i];
        float4 b = ((const float4*)nf)[i];
        ushort4 r;
        r.x = f2bf(__fmul_rn(a.x, b.x));
        r.y = f2bf(__fmul_rn(a.y, b.y));
        r.z = f2bf(__fmul_rn(a.z, b.z));
        r.w = f2bf(__fmul_rn(a.w, b.w));
        ((ushort4*)P)[i] = r;
    }
}

// ---------------- ball query: one anchor per wave, ballot ordered extraction ----------------
__global__ __launch_bounds__(256) void k_ball(const float* __restrict__ anchor,
                                              const float* __restrict__ neighbor,
                                              int* __restrict__ idx) {
    int lane = threadIdx.x & 63;
    int an = blockIdx.x * 4 + (threadIdx.x >> 6);   // 0..8191
    int b = an >> 12;
    const float* nb = neighbor + (size_t)b * NN * 3;

    float ax = anchor[an * 3 + 0];
    float ay = anchor[an * 3 + 1];
    float az = anchor[an * 3 + 2];

    unsigned long long lmask = (lane == 63) ? 0xFFFFFFFFFFFFFFFFull >> 1
                                            : ((1ull << lane) - 1ull);
    int cnt = 0;
    int firstIdx = -1;
    int* myout = idx + (size_t)an * KNN;

    for (int chunk = 0; chunk < NN / 64 && cnt < KNN; ++chunk) {
        int j = chunk * 64 + lane;
        float dx = __fsub_rn(ax, nb[j * 3 + 0]);
        float dy = __fsub_rn(ay, nb[j * 3 + 1]);
        float dz = __fsub_rn(az, nb[j * 3 + 2]);
        float d2 = __fadd_rn(__fadd_rn(__fmul_rn(dx, dx), __fmul_rn(dy, dy)),
                             __fmul_rn(dz, dz));
        bool hit = d2 < 1.0f;
        unsigned long long m = __ballot(hit);
        if (m) {
            int pos = cnt + __popcll(m & lmask);
            if (hit && pos < KNN) myout[pos] = j;
            if (firstIdx < 0) firstIdx = chunk * 64 + (__ffsll((long long)m) - 1);
            cnt += __popcll(m);
        }
    }
    if (cnt < KNN) {
        int f = (firstIdx < 0) ? 0 : firstIdx;
        if (lane >= cnt && lane < KNN) myout[lane] = f;
    }
}

// ======================= GEMM0 (MFMA, LDS-free): gather + X@W0p^T, relu, stats =======================
// X fragments loaded straight from gathered P rows; dxyz computed in-register (k 64..66).
// W0p fragments loaded from global (24 KB, L1-resident).
__global__ __launch_bounds__(256) void k_gemm0(const float* __restrict__ anchor,
                                               const float* __restrict__ neighbor,
                                               const unsigned short* __restrict__ P,
                                               const int* __restrict__ idx,
                                               const short* __restrict__ W0p,
                                               unsigned short* __restrict__ y0,
                                               float* __restrict__ stats) {
    __shared__ float sred[CO * 2];
    int t = threadIdx.x;
    int rowBase = blockIdx.x * 128;
    sred[t] = 0.0f;          // t < 256 == CO*2
    __syncthreads();

    int lane = t & 63, w = t >> 6;
    int lm = lane & 15, g = lane >> 4;

    // ---- X fragments: 2 row-subtiles (i), 3 k-chunks ----
    bf16x8 xf[2][3];
#pragma unroll
    for (int i = 0; i < 2; ++i) {
        int r = rowBase + w * 32 + i * 16 + lm;
        int bn = r >> 4;            // uniform across lm
        int bb = r >> 16;
        int j = idx[r];
        const unsigned short* Prow = P + ((size_t)(bb << 12) + j) * CC;
        xf[i][0] = *(const bf16x8*)(Prow + g * 8);
        xf[i][1] = *(const bf16x8*)(Prow + 32 + g * 8);
        bf16x8 x2 = {0, 0, 0, 0, 0, 0, 0, 0};
        if (g == 0) {
            const float* nbr = neighbor + ((size_t)(bb << 12) + j) * 3;
            float dx = __fsub_rn(anchor[bn * 3 + 0], nbr[0]);
            float dy = __fsub_rn(anchor[bn * 3 + 1], nbr[1]);
            float dz = __fsub_rn(anchor[bn * 3 + 2], nbr[2]);
            x2[0] = (short)f2bf(dx);
            x2[1] = (short)f2bf(dy);
            x2[2] = (short)f2bf(dz);
        }
        xf[i][2] = x2;
    }

    f32x4 zero = {0.f, 0.f, 0.f, 0.f};
    f32x4 acc[2][8];
#pragma unroll
    for (int i = 0; i < 2; ++i)
#pragma unroll
        for (int c = 0; c < 8; ++c) acc[i][c] = zero;

#pragma unroll
    for (int kc = 0; kc < 3; ++kc) {
        int koff = kc * 32 + g * 8;
#pragma unroll
        for (int ct = 0; ct < 8; ++ct) {
            bf16x8 wf = *(const bf16x8*)&W0p[(ct * 16 + lm) * K0P + koff];
            acc[0][ct] = __builtin_amdgcn_mfma_f32_16x16x32_bf16(xf[0][kc], wf, acc[0][ct], 0, 0, 0);
            acc[1][ct] = __builtin_amdgcn_mfma_f32_16x16x32_bf16(xf[1][kc], wf, acc[1][ct], 0, 0, 0);
        }
    }

    // epilogue: relu, store bf16, stats (on relu'd values)
#pragma unroll
    for (int ct = 0; ct < 8; ++ct) {
        int o = lm + 16 * ct;
        float psum = 0.f, psq = 0.f;
#pragma unroll
        for (int i = 0; i < 2; ++i) {
#pragma unroll
            for (int rg = 0; rg < 4; ++rg) {
                float v = fmaxf(acc[i][ct][rg], 0.0f);
                int r = rowBase + w * 32 + i * 16 + g * 4 + rg;
                y0[(size_t)r * CO + o] = f2bf(v);
                psum += v; psq += v * v;
            }
        }
        psum += __shfl_xor(psum, 16); psq += __shfl_xor(psq, 16);
        psum += __shfl_xor(psum, 32); psq += __shfl_xor(psq, 32);
        if (lane < 16) {
            atomicAdd(&sred[o * 2 + 0], psum);
            atomicAdd(&sred[o * 2 + 1], psq);
        }
    }
    __syncthreads();
    int slot = blockIdx.x & 15;
    atomicAdd(&stats[slot * CO * 2 + t], sred[t]);
}

// ======================= GEMM 1/2 (MFMA) =======================
// A (rows of transformed X) loaded straight from global bf16; prep'd bf16 W staged in LDS.
// MODE 1: x = v*sc+sh        MODE 2: x = relu(v*sc+sh)
#define WST 136   // 128 + 8 pad
template<int MODE>
__global__ __launch_bounds__(256) void k_gemm12(const unsigned short* __restrict__ Xin,
                                                const short* __restrict__ Wp,
                                                const float* __restrict__ bnp,
                                                unsigned short* __restrict__ Hout,
                                                float* __restrict__ stats) {
    __shared__ alignas(16) short Wl[128 * WST];
    __shared__ float ssc[CO];
    __shared__ float ssh[CO];
    __shared__ float sred[CO * 2];
    int t = threadIdx.x;
    int rowBase = blockIdx.x * 128;

    if (t < 128) ssc[t] = bnp[t];
    else         ssh[t - 128] = bnp[t];
    sred[t] = 0.0f;

    // stage prep'd bf16 W -> LDS (coalesced uint4)
#pragma unroll
    for (int q = 0; q < 8; ++q) {
        int e = (q * 256 + t) * 8;       // element index
        int o = e >> 7, k = e & 127;
        *(uint4*)&Wl[o * WST + k] = *(const uint4*)&Wp[e];
    }
    __syncthreads();

    int lane = t & 63, w = t >> 6;
    int lm = lane & 15, g = lane >> 4;
    f32x4 zero = {0.f, 0.f, 0.f, 0.f};
    f32x4 acc[2][8];
#pragma unroll
    for (int i = 0; i < 2; ++i)
#pragma unroll
        for (int c = 0; c < 8; ++c) acc[i][c] = zero;

#pragma unroll
    for (int kc = 0; kc < 4; ++kc) {
        int k0 = kc * 32 + g * 8;
        float4 sc0 = *(const float4*)&ssc[k0];
        float4 sc1 = *(const float4*)&ssc[k0 + 4];
        float4 sh0 = *(const float4*)&ssh[k0];
        float4 sh1 = *(const float4*)&ssh[k0 + 4];
        float scv[8] = {sc0.x, sc0.y, sc0.z, sc0.w, sc1.x, sc1.y, sc1.z, sc1.w};
        float shv[8] = {sh0.x, sh0.y, sh0.z, sh0.w, sh1.x, sh1.y, sh1.z, sh1.w};

        bf16x8 afr[2];
#pragma unroll
        for (int i = 0; i < 2; ++i) {
            int r = rowBase + w * 32 + i * 16 + lm;
            U16B u;
            u.v = *(const uint4*)(Xin + (size_t)r * CO + k0);
#pragma unroll
            for (int j = 0; j < 8; ++j) {
                float v = bf2f(u.us[j]) * scv[j] + shv[j];
                if (MODE == 2) v = fmaxf(v, 0.0f);
                afr[i][j] = (short)f2bf(v);
            }
        }
#pragma unroll
        for (int ct = 0; ct < 8; ++ct) {
            bf16x8 bfr = *(const bf16x8*)&Wl[(ct * 16 + lm) * WST + k0];
#pragma unroll
            for (int i = 0; i < 2; ++i)
                acc[i][ct] = __builtin_amdgcn_mfma_f32_16x16x32_bf16(afr[i], bfr, acc[i][ct], 0, 0, 0);
        }
    }

    // epilogue: store raw bf16 + stats on raw values
#pragma unroll
    for (int ct = 0; ct < 8; ++ct) {
        int o = lm + 16 * ct;
        float psum = 0.f, psq = 0.f;
#pragma unroll
        for (int i = 0; i < 2; ++i) {
#pragma unroll
            for (int rg = 0; rg < 4; ++rg) {
                float v = acc[i][ct][rg];
                int r = rowBase + w * 32 + i * 16 + g * 4 + rg;
                Hout[(size_t)r * CO + o] = f2bf(v);
                psum += v; psq += v * v;
            }
        }
        psum += __shfl_xor(psum, 16); psq += __shfl_xor(psq, 16);
        psum += __shfl_xor(psum, 32); psq += __shfl_xor(psq, 32);
        if (lane < 16) {
            atomicAdd(&sred[o * 2 + 0], psum);
            atomicAdd(&sred[o * 2 + 1], psq);
        }
    }
    __syncthreads();
    int slot = blockIdx.x & 15;
    atomicAdd(&stats[slot * CO * 2 + t], sred[t]);
}

// ---------------- BN finalize: sc[128] then sh[128] ----------------
__global__ void k_bnfin(const float* __restrict__ stats, const float* __restrict__ gamma,
                        const float* __restrict__ beta, float* __restrict__ bnp) {
    int o = threadIdx.x;  // 128
    float S = 0.0f, Q = 0.0f;
    for (int s = 0; s < 16; ++s) {
        S += stats[s * CO * 2 + o * 2 + 0];
        Q += stats[s * CO * 2 + o * 2 + 1];
    }
    float inv = 1.0f / (float)ROWS;
    float mean = S * inv;
    float var = Q * inv - mean * mean;
    float sc = gamma[o] * rsqrtf(var + 1e-5f);
    bnp[o] = sc;
    bnp[o + 128] = beta[o] - mean * sc;
}

// ---------------- output: one wave per point; max over K of relu(BN2(h2)) ----------------
__global__ __launch_bounds__(256) void k_out(const unsigned short* __restrict__ h2,
                                             const float* __restrict__ bnp,
                                             float* __restrict__ out) {
    int lane = threadIdx.x & 63, w = threadIdx.x >> 6;
    int bn = blockIdx.x * 4 + w;          // 0..8191
    int lm = lane & 15, g = lane >> 4;
    const unsigned short* base = h2 + (size_t)bn * KNN * CO;

    float4 sc0 = *(const float4*)&bnp[lm * 8];
    float4 sc1 = *(const float4*)&bnp[lm * 8 + 4];
    float4 sh0 = *(const float4*)&bnp[128 + lm * 8];
    float4 sh1 = *(const float4*)&bnp[128 + lm * 8 + 4];
    float scv[8] = {sc0.x, sc0.y, sc0.z, sc0.w, sc1.x, sc1.y, sc1.z, sc1.w};
    float shv[8] = {sh0.x, sh0.y, sh0.z, sh0.w, sh1.x, sh1.y, sh1.z, sh1.w};

    float m[8] = {0.f, 0.f, 0.f, 0.f, 0.f, 0.f, 0.f, 0.f};   // relu floor
#pragma unroll
    for (int rr = 0; rr < 4; ++rr) {
        U16B u;
        u.v = *(const uint4*)&base[(rr * 4 + g) * CO + lm * 8];
#pragma unroll
        for (int j = 0; j < 8; ++j) {
            float v = bf2f(u.us[j]) * scv[j] + shv[j];
            m[j] = fmaxf(m[j], v);
        }
    }
#pragma unroll
    for (int j = 0; j < 8; ++j) m[j] = fmaxf(m[j], __shfl_xor(m[j], 16));
#pragma unroll
    for (int j = 0; j < 8; ++j) m[j] = fmaxf(m[j], __shfl_xor(m[j], 32));
    if (g == 0) {
        float4 a = {m[0], m[1], m[2], m[3]};
        float4 b = {m[4], m[5], m[6], m[7]};
        *(float4*)&out[(size_t)bn * CO + lm * 8] = a;
        *(float4*)&out[(size_t)bn * CO + lm * 8 + 4] = b;
    }
}

extern "C" void kernel_launch(void* const* d_in, const int* in_sizes, int n_in,
                              void* d_out, int out_size, void* d_ws, size_t ws_size,
                              hipStream_t stream) {
    (void)in_sizes; (void)n_in; (void)out_size; (void)ws_size;
    const float* anchor = (const float*)d_in[0];
    const float* neighbor = (const float*)d_in[1];
    const float* nfeat = (const float*)d_in[2];
    const float* feat = (const float*)d_in[3];
    const float* W0 = (const float*)d_in[4];
    const float* g0 = (const float*)d_in[5];
    const float* b0 = (const float*)d_in[6];
    const float* W1 = (const float*)d_in[7];
    const float* g1 = (const float*)d_in[8];
    const float* b1 = (const float*)d_in[9];
    const float* W2 = (const float*)d_in[10];
    const float* g2 = (const float*)d_in[11];
    const float* b2 = (const float*)d_in[12];
    float* out = (float*)d_out;

    char* ws = (char*)d_ws;
    size_t o_idx = 0;                                   // 512 KB
    size_t o_P = o_idx + (size_t)ROWS * 4;              // bf16 P: 1 MB
    size_t o_stats = o_P + (size_t)BB * NN * CC * 2;
    size_t o_bnp = o_stats + 3 * 16 * CO * 2 * 4;
    size_t o_W0p = o_bnp + 3 * CO * 2 * 4;              // 128*96*2 = 24576
    size_t o_W12p = o_W0p + 128 * K0P * 2;              // 2*16384*2 = 65536
    size_t o_bufA = (o_W12p + 32768 * 2 + 255) & ~(size_t)255;
    size_t o_bufB = o_bufA + (size_t)ROWS * CO * 2;     // bf16 buffers: 32 MB each

    int* idx = (int*)(ws + o_idx);
    unsigned short* P = (unsigned short*)(ws + o_P);
    float* stats0 = (float*)(ws + o_stats);
    float* stats1 = stats0 + 16 * CO * 2;
    float* stats2 = stats1 + 16 * CO * 2;
    float* bnp0 = (float*)(ws + o_bnp);
    float* bnp1 = bnp0 + CO * 2;
    float* bnp2 = bnp1 + CO * 2;
    short* W0p = (short*)(ws + o_W0p);
    short* W12p = (short*)(ws + o_W12p);
    unsigned short* bufA = (unsigned short*)(ws + o_bufA);   // y0, later h2
    unsigned short* bufB = (unsigned short*)(ws + o_bufB);   // h1

    hipMemsetAsync(ws + o_stats, 0, 3 * 16 * CO * 2 * 4, stream);

    k_prep<<<(128 * K0P + 32768 + 255) / 256, 256, 0, stream>>>(W0, W1, W2, W0p, W12p);
    k_prod<<<BB * NN * CC / 4 / 256, 256, 0, stream>>>(feat, nfeat, P);
    k_ball<<<BB * NN / 4, 256, 0, stream>>>(anchor, neighbor, idx);
    k_gemm0<<<ROWS / 128, 256, 0, stream>>>(anchor, neighbor, P, idx, W0p, bufA, stats0);
    k_bnfin<<<1, CO, 0, stream>>>(stats0, g0, b0, bnp0);
    k_gemm12<1><<<ROWS / 128, 256, 0, stream>>>(bufA, W12p, bnp0, bufB, stats1);
    k_bnfin<<<1, CO, 0, stream>>>(stats1, g1, b1, bnp1);
    k_gemm12<2><<<ROWS / 128, 256, 0, stream>>>(bufB, W12p + 16384, bnp1, bufA, stats2);
    k_bnfin<<<1, CO, 0, stream>>>(stats2, g2, b2, bnp2);
    k_out<<<BB * NN / 4, 256, 0, stream>>>(bufA, bnp2, out);
}

// Round 8
// 116.040 us; speedup vs baseline: 7.2240x; 1.0544x over previous
//
#include <hip/hip_runtime.h>
#include <hip/hip_bf16.h>

#define BB 2
#define NN 4096
#define KNN 16
#define CC 64
#define CO 128
#define ROWS (BB*NN*KNN)   // 131072
#define K0P 96             // padded/permuted K for layer 0
#define NSLOT 16

typedef __attribute__((ext_vector_type(8))) short bf16x8;
typedef __attribute__((ext_vector_type(4))) float f32x4;

__device__ __forceinline__ float bf2f(unsigned short u) {
    return __uint_as_float(((unsigned)u) << 16);
}
__device__ __forceinline__ unsigned short f2bf(float f) {
    __hip_bfloat16 h = __float2bfloat16(f);
    return *reinterpret_cast<unsigned short*>(&h);
}

union U16B { uint4 v; unsigned short us[8]; };

// ---------------- prep: zero stats; W0 col-permuted+padded, W1/W2 converted, all bf16 ----------------
// W0p[o][k]: k 0..63 = W0[o][3+k], k 64..66 = W0[o][k-64], k 67..95 = 0.  (matches X layout)
__global__ void k_prep(const float* __restrict__ W0, const float* __restrict__ W1,
                       const float* __restrict__ W2,
                       short* __restrict__ W0p, short* __restrict__ W12p,
                       float* __restrict__ stats) {
    int i = blockIdx.x * 256 + threadIdx.x;
    if (i < 3 * NSLOT * CO * 2) stats[i] = 0.0f;      // 12288 floats
    if (i < 128 * K0P) {
        int o = i / K0P, k = i - o * K0P;
        float v;
        if (k < 64)      v = W0[o * 67 + 3 + k];
        else if (k < 67) v = W0[o * 67 + (k - 64)];
        else             v = 0.0f;
        W0p[i] = (short)f2bf(v);
    } else if (i < 128 * K0P + 16384) {
        int e = i - 128 * K0P;
        W12p[e] = (short)f2bf(W1[e]);
    } else if (i < 128 * K0P + 32768) {
        int e = i - 128 * K0P - 16384;
        W12p[16384 + e] = (short)f2bf(W2[e]);
    }
}

// ---------------- P = features * neighbor_features  (bf16 out) ----------------
__global__ void k_prod(const float* __restrict__ f, const float* __restrict__ nf,
                       unsigned short* __restrict__ P) {
    int i = blockIdx.x * blockDim.x + threadIdx.x;
    int total = BB * NN * CC / 4;
    if (i < total) {
        float4 a = ((const float4*)f)[i];
        float4 b = ((const float4*)nf)[i];
        ushort4 r;
        r.x = f2bf(__fmul_rn(a.x, b.x));
        r.y = f2bf(__fmul_rn(a.y, b.y));
        r.z = f2bf(__fmul_rn(a.z, b.z));
        r.w = f2bf(__fmul_rn(a.w, b.w));
        ((ushort4*)P)[i] = r;
    }
}

// ---------------- ball query: one anchor per wave, ballot ordered extraction ----------------
__global__ __launch_bounds__(256) void k_ball(const float* __restrict__ anchor,
                                              const float* __restrict__ neighbor,
                                              int* __restrict__ idx) {
    int lane = threadIdx.x & 63;
    int an = blockIdx.x * 4 + (threadIdx.x >> 6);   // 0..8191
    int b = an >> 12;
    const float* nb = neighbor + (size_t)b * NN * 3;

    float ax = anchor[an * 3 + 0];
    float ay = anchor[an * 3 + 1];
    float az = anchor[an * 3 + 2];

    unsigned long long lmask = (lane == 63) ? 0xFFFFFFFFFFFFFFFFull >> 1
                                            : ((1ull << lane) - 1ull);
    int cnt = 0;
    int firstIdx = -1;
    int* myout = idx + (size_t)an * KNN;

    for (int chunk = 0; chunk < NN / 64 && cnt < KNN; ++chunk) {
        int j = chunk * 64 + lane;
        float dx = __fsub_rn(ax, nb[j * 3 + 0]);
        float dy = __fsub_rn(ay, nb[j * 3 + 1]);
        float dz = __fsub_rn(az, nb[j * 3 + 2]);
        float d2 = __fadd_rn(__fadd_rn(__fmul_rn(dx, dx), __fmul_rn(dy, dy)),
                             __fmul_rn(dz, dz));
        bool hit = d2 < 1.0f;
        unsigned long long m = __ballot(hit);
        if (m) {
            int pos = cnt + __popcll(m & lmask);
            if (hit && pos < KNN) myout[pos] = j;
            if (firstIdx < 0) firstIdx = chunk * 64 + (__ffsll((long long)m) - 1);
            cnt += __popcll(m);
        }
    }
    if (cnt < KNN) {
        int f = (firstIdx < 0) ? 0 : firstIdx;
        if (lane >= cnt && lane < KNN) myout[lane] = f;
    }
}

// ======================= GEMM0 (MFMA, LDS-free): gather + X@W0p^T, relu, stats =======================
__global__ __launch_bounds__(256) void k_gemm0(const float* __restrict__ anchor,
                                               const float* __restrict__ neighbor,
                                               const unsigned short* __restrict__ P,
                                               const int* __restrict__ idx,
                                               const short* __restrict__ W0p,
                                               unsigned short* __restrict__ y0,
                                               float* __restrict__ stats) {
    __shared__ float sred[CO * 2];
    int t = threadIdx.x;
    int rowBase = blockIdx.x * 128;
    sred[t] = 0.0f;          // t < 256 == CO*2
    __syncthreads();

    int lane = t & 63, w = t >> 6;
    int lm = lane & 15, g = lane >> 4;

    // ---- X fragments: 2 row-subtiles (i), 3 k-chunks ----
    bf16x8 xf[2][3];
#pragma unroll
    for (int i = 0; i < 2; ++i) {
        int r = rowBase + w * 32 + i * 16 + lm;
        int bn = r >> 4;            // b*4096+n
        int bb = r >> 16;
        int j = idx[r];
        const unsigned short* Prow = P + ((size_t)(bb << 12) + j) * CC;
        xf[i][0] = *(const bf16x8*)(Prow + g * 8);
        xf[i][1] = *(const bf16x8*)(Prow + 32 + g * 8);
        bf16x8 x2 = {0, 0, 0, 0, 0, 0, 0, 0};
        if (g == 0) {
            const float* nbr = neighbor + ((size_t)(bb << 12) + j) * 3;
            float dx = __fsub_rn(anchor[bn * 3 + 0], nbr[0]);
            float dy = __fsub_rn(anchor[bn * 3 + 1], nbr[1]);
            float dz = __fsub_rn(anchor[bn * 3 + 2], nbr[2]);
            x2[0] = (short)f2bf(dx);
            x2[1] = (short)f2bf(dy);
            x2[2] = (short)f2bf(dz);
        }
        xf[i][2] = x2;
    }

    f32x4 zero = {0.f, 0.f, 0.f, 0.f};
    f32x4 acc[2][8];
#pragma unroll
    for (int i = 0; i < 2; ++i)
#pragma unroll
        for (int c = 0; c < 8; ++c) acc[i][c] = zero;

#pragma unroll
    for (int kc = 0; kc < 3; ++kc) {
        int koff = kc * 32 + g * 8;
#pragma unroll
        for (int ct = 0; ct < 8; ++ct) {
            bf16x8 wf = *(const bf16x8*)&W0p[(ct * 16 + lm) * K0P + koff];
            acc[0][ct] = __builtin_amdgcn_mfma_f32_16x16x32_bf16(xf[0][kc], wf, acc[0][ct], 0, 0, 0);
            acc[1][ct] = __builtin_amdgcn_mfma_f32_16x16x32_bf16(xf[1][kc], wf, acc[1][ct], 0, 0, 0);
        }
    }

    // epilogue: relu, store bf16, stats (on relu'd values)
#pragma unroll
    for (int ct = 0; ct < 8; ++ct) {
        int o = lm + 16 * ct;
        float psum = 0.f, psq = 0.f;
#pragma unroll
        for (int i = 0; i < 2; ++i) {
#pragma unroll
            for (int rg = 0; rg < 4; ++rg) {
                float v = fmaxf(acc[i][ct][rg], 0.0f);
                int r = rowBase + w * 32 + i * 16 + g * 4 + rg;
                y0[(size_t)r * CO + o] = f2bf(v);
                psum += v; psq += v * v;
            }
        }
        psum += __shfl_xor(psum, 16); psq += __shfl_xor(psq, 16);
        psum += __shfl_xor(psum, 32); psq += __shfl_xor(psq, 32);
        if (lane < 16) {
            atomicAdd(&sred[o * 2 + 0], psum);
            atomicAdd(&sred[o * 2 + 1], psq);
        }
    }
    __syncthreads();
    int slot = blockIdx.x & (NSLOT - 1);
    atomicAdd(&stats[slot * CO * 2 + t], sred[t]);
}

// ======================= GEMM 1/2 (MFMA, fused BN-finalize prologue) =======================
// Computes sc/sh from prev-layer stats in-block; A rows from global bf16; W staged in LDS.
// MODE 1: x = v*sc+sh        MODE 2: x = relu(v*sc+sh)
#define WST 136   // 128 + 8 pad
template<int MODE>
__global__ __launch_bounds__(256) void k_gemm12(const unsigned short* __restrict__ Xin,
                                                const short* __restrict__ Wp,
                                                const float* __restrict__ statsIn,
                                                const float* __restrict__ gamma,
                                                const float* __restrict__ beta,
                                                unsigned short* __restrict__ Hout,
                                                float* __restrict__ statsOut) {
    __shared__ alignas(16) short Wl[128 * WST];
    __shared__ float ssc[CO];
    __shared__ float ssh[CO];
    __shared__ float sred[CO * 2];
    int t = threadIdx.x;
    int rowBase = blockIdx.x * 128;

    sred[t] = 0.0f;
    if (t < 128) {
        float S = 0.0f, Q = 0.0f;
#pragma unroll
        for (int s = 0; s < NSLOT; ++s) {
            S += statsIn[s * CO * 2 + t * 2 + 0];
            Q += statsIn[s * CO * 2 + t * 2 + 1];
        }
        float inv = 1.0f / (float)ROWS;
        float mean = S * inv;
        float var = Q * inv - mean * mean;
        float sc = gamma[t] * rsqrtf(var + 1e-5f);
        ssc[t] = sc;
        ssh[t] = beta[t] - mean * sc;
    }

    // stage prep'd bf16 W -> LDS (coalesced uint4)
#pragma unroll
    for (int q = 0; q < 8; ++q) {
        int e = (q * 256 + t) * 8;       // element index
        int o = e >> 7, k = e & 127;
        *(uint4*)&Wl[o * WST + k] = *(const uint4*)&Wp[e];
    }
    __syncthreads();

    int lane = t & 63, w = t >> 6;
    int lm = lane & 15, g = lane >> 4;
    f32x4 zero = {0.f, 0.f, 0.f, 0.f};
    f32x4 acc[2][8];
#pragma unroll
    for (int i = 0; i < 2; ++i)
#pragma unroll
        for (int c = 0; c < 8; ++c) acc[i][c] = zero;

#pragma unroll
    for (int kc = 0; kc < 4; ++kc) {
        int k0 = kc * 32 + g * 8;
        float4 sc0 = *(const float4*)&ssc[k0];
        float4 sc1 = *(const float4*)&ssc[k0 + 4];
        float4 sh0 = *(const float4*)&ssh[k0];
        float4 sh1 = *(const float4*)&ssh[k0 + 4];
        float scv[8] = {sc0.x, sc0.y, sc0.z, sc0.w, sc1.x, sc1.y, sc1.z, sc1.w};
        float shv[8] = {sh0.x, sh0.y, sh0.z, sh0.w, sh1.x, sh1.y, sh1.z, sh1.w};

        bf16x8 afr[2];
#pragma unroll
        for (int i = 0; i < 2; ++i) {
            int r = rowBase + w * 32 + i * 16 + lm;
            U16B u;
            u.v = *(const uint4*)(Xin + (size_t)r * CO + k0);
#pragma unroll
            for (int j = 0; j < 8; ++j) {
                float v = bf2f(u.us[j]) * scv[j] + shv[j];
                if (MODE == 2) v = fmaxf(v, 0.0f);
                afr[i][j] = (short)f2bf(v);
            }
        }
#pragma unroll
        for (int ct = 0; ct < 8; ++ct) {
            bf16x8 bfr = *(const bf16x8*)&Wl[(ct * 16 + lm) * WST + k0];
#pragma unroll
            for (int i = 0; i < 2; ++i)
                acc[i][ct] = __builtin_amdgcn_mfma_f32_16x16x32_bf16(afr[i], bfr, acc[i][ct], 0, 0, 0);
        }
    }

    // epilogue: store raw bf16 + stats on raw values
#pragma unroll
    for (int ct = 0; ct < 8; ++ct) {
        int o = lm + 16 * ct;
        float psum = 0.f, psq = 0.f;
#pragma unroll
        for (int i = 0; i < 2; ++i) {
#pragma unroll
            for (int rg = 0; rg < 4; ++rg) {
                float v = acc[i][ct][rg];
                int r = rowBase + w * 32 + i * 16 + g * 4 + rg;
                Hout[(size_t)r * CO + o] = f2bf(v);
                psum += v; psq += v * v;
            }
        }
        psum += __shfl_xor(psum, 16); psq += __shfl_xor(psq, 16);
        psum += __shfl_xor(psum, 32); psq += __shfl_xor(psq, 32);
        if (lane < 16) {
            atomicAdd(&sred[o * 2 + 0], psum);
            atomicAdd(&sred[o * 2 + 1], psq);
        }
    }
    __syncthreads();
    int slot = blockIdx.x & (NSLOT - 1);
    atomicAdd(&statsOut[slot * CO * 2 + t], sred[t]);
}

// ---------------- output: fused BN2-finalize; one wave per point; max over K of relu(BN2(h2)) ----------------
__global__ __launch_bounds__(256) void k_out(const unsigned short* __restrict__ h2,
                                             const float* __restrict__ statsIn,
                                             const float* __restrict__ gamma,
                                             const float* __restrict__ beta,
                                             float* __restrict__ out) {
    __shared__ float ssc[CO];
    __shared__ float ssh[CO];
    int t = threadIdx.x;
    if (t < 128) {
        float S = 0.0f, Q = 0.0f;
#pragma unroll
        for (int s = 0; s < NSLOT; ++s) {
            S += statsIn[s * CO * 2 + t * 2 + 0];
            Q += statsIn[s * CO * 2 + t * 2 + 1];
        }
        float inv = 1.0f / (float)ROWS;
        float mean = S * inv;
        float var = Q * inv - mean * mean;
        float sc = gamma[t] * rsqrtf(var + 1e-5f);
        ssc[t] = sc;
        ssh[t] = beta[t] - mean * sc;
    }
    __syncthreads();

    int lane = t & 63, w = t >> 6;
    int bn = blockIdx.x * 4 + w;          // 0..8191
    int lm = lane & 15, g = lane >> 4;
    const unsigned short* base = h2 + (size_t)bn * KNN * CO;

    float scv[8], shv[8];
#pragma unroll
    for (int j = 0; j < 8; ++j) { scv[j] = ssc[lm * 8 + j]; shv[j] = ssh[lm * 8 + j]; }

    float m[8] = {0.f, 0.f, 0.f, 0.f, 0.f, 0.f, 0.f, 0.f};   // relu floor
#pragma unroll
    for (int rr = 0; rr < 4; ++rr) {
        U16B u;
        u.v = *(const uint4*)&base[(rr * 4 + g) * CO + lm * 8];
#pragma unroll
        for (int j = 0; j < 8; ++j) {
            float v = bf2f(u.us[j]) * scv[j] + shv[j];
            m[j] = fmaxf(m[j], v);
        }
    }
#pragma unroll
    for (int j = 0; j < 8; ++j) m[j] = fmaxf(m[j], __shfl_xor(m[j], 16));
#pragma unroll
    for (int j = 0; j < 8; ++j) m[j] = fmaxf(m[j], __shfl_xor(m[j], 32));
    if (g == 0) {
        float4 a = {m[0], m[1], m[2], m[3]};
        float4 b = {m[4], m[5], m[6], m[7]};
        *(float4*)&out[(size_t)bn * CO + lm * 8] = a;
        *(float4*)&out[(size_t)bn * CO + lm * 8 + 4] = b;
    }
}

extern "C" void kernel_launch(void* const* d_in, const int* in_sizes, int n_in,
                              void* d_out, int out_size, void* d_ws, size_t ws_size,
                              hipStream_t stream) {
    (void)in_sizes; (void)n_in; (void)out_size; (void)ws_size;
    const float* anchor = (const float*)d_in[0];
    const float* neighbor = (const float*)d_in[1];
    const float* nfeat = (const float*)d_in[2];
    const float* feat = (const float*)d_in[3];
    const float* W0 = (const float*)d_in[4];
    const float* g0 = (const float*)d_in[5];
    const float* b0 = (const float*)d_in[6];
    const float* W1 = (const float*)d_in[7];
    const float* g1 = (const float*)d_in[8];
    const float* b1 = (const float*)d_in[9];
    const float* W2 = (const float*)d_in[10];
    const float* g2 = (const float*)d_in[11];
    const float* b2 = (const float*)d_in[12];
    float* out = (float*)d_out;

    char* ws = (char*)d_ws;
    size_t o_idx = 0;                                   // 512 KB
    size_t o_P = o_idx + (size_t)ROWS * 4;              // bf16 P: 1 MB
    size_t o_stats = o_P + (size_t)BB * NN * CC * 2;
    size_t o_W0p = o_stats + 3 * NSLOT * CO * 2 * 4;    // 128*96*2 = 24576
    size_t o_W12p = o_W0p + 128 * K0P * 2;              // 2*16384*2 = 65536
    size_t o_bufA = (o_W12p + 32768 * 2 + 255) & ~(size_t)255;
    size_t o_bufB = o_bufA + (size_t)ROWS * CO * 2;     // bf16 buffers: 32 MB each

    int* idx = (int*)(ws + o_idx);
    unsigned short* P = (unsigned short*)(ws + o_P);
    float* stats0 = (float*)(ws + o_stats);
    float* stats1 = stats0 + NSLOT * CO * 2;
    float* stats2 = stats1 + NSLOT * CO * 2;
    short* W0p = (short*)(ws + o_W0p);
    short* W12p = (short*)(ws + o_W12p);
    unsigned short* bufA = (unsigned short*)(ws + o_bufA);   // y0, later h2
    unsigned short* bufB = (unsigned short*)(ws + o_bufB);   // h1

    k_prep<<<(128 * K0P + 32768 + 255) / 256, 256, 0, stream>>>(W0, W1, W2, W0p, W12p, stats0);
    k_prod<<<BB * NN * CC / 4 / 256, 256, 0, stream>>>(feat, nfeat, P);
    k_ball<<<BB * NN / 4, 256, 0, stream>>>(anchor, neighbor, idx);
    k_gemm0<<<ROWS / 128, 256, 0, stream>>>(anchor, neighbor, P, idx, W0p, bufA, stats0);
    k_gemm12<1><<<ROWS / 128, 256, 0, stream>>>(bufA, W12p, stats0, g0, b0, bufB, stats1);
    k_gemm12<2><<<ROWS / 128, 256, 0, stream>>>(bufB, W12p + 16384, stats1, g1, b1, bufA, stats2);
    k_out<<<BB * NN / 4, 256, 0, stream>>>(bufA, stats2, g2, b2, out);
}

// Round 9
// 112.558 us; speedup vs baseline: 7.4475x; 1.0309x over previous
//
#include <hip/hip_runtime.h>
#include <hip/hip_bf16.h>

#define BB 2
#define NN 4096
#define KNN 16
#define CC 64
#define CO 128
#define ROWS (BB*NN*KNN)   // 131072
#define K0P 96             // padded/permuted K for layer 0
#define NSLOT 16
#define WST 136            // 128 + 8 pad (bf16 elems)

// k_pre block ranges
#define PRE_PREP 112       // covers i < 28672
#define PRE_PROD 512       // 131072 float4 elems
#define PRE_BALL 2048      // 8192 anchors / 4 per block

typedef __attribute__((ext_vector_type(8))) short bf16x8;
typedef __attribute__((ext_vector_type(4))) float f32x4;

__device__ __forceinline__ float bf2f(unsigned short u) {
    return __uint_as_float(((unsigned)u) << 16);
}
__device__ __forceinline__ unsigned short f2bf(float f) {
    __hip_bfloat16 h = __float2bfloat16(f);
    return *reinterpret_cast<unsigned short*>(&h);
}

union U16B { uint4 v; unsigned short us[8]; };

// ======================= k_pre: stats-zero + W0 permute/cvt + W2 cvt + prod + ball =======================
__global__ __launch_bounds__(256) void k_pre(const float* __restrict__ anchor,
                                             const float* __restrict__ neighbor,
                                             const float* __restrict__ feat,
                                             const float* __restrict__ nfeat,
                                             const float* __restrict__ W0,
                                             const float* __restrict__ W2,
                                             short* __restrict__ W0p,
                                             short* __restrict__ W2p,
                                             float* __restrict__ stats,
                                             int* __restrict__ idx,
                                             unsigned short* __restrict__ P) {
    int blk = blockIdx.x;
    int t = threadIdx.x;
    if (blk < PRE_PREP) {
        int i = blk * 256 + t;
        if (i < 3 * NSLOT * CO * 2) stats[i] = 0.0f;          // 12288 floats
        if (i < 128 * K0P) {                                   // 12288
            int o = i / K0P, k = i - o * K0P;
            float v;
            if (k < 64)      v = W0[o * 67 + 3 + k];
            else if (k < 67) v = W0[o * 67 + (k - 64)];
            else             v = 0.0f;
            W0p[i] = (short)f2bf(v);
        } else if (i < 128 * K0P + 16384) {
            int e = i - 128 * K0P;
            W2p[e] = (short)f2bf(W2[e]);
        }
    } else if (blk < PRE_PREP + PRE_PROD) {
        int i = (blk - PRE_PREP) * 256 + t;                    // < 131072
        float4 a = ((const float4*)feat)[i];
        float4 b = ((const float4*)nfeat)[i];
        ushort4 r;
        r.x = f2bf(__fmul_rn(a.x, b.x));
        r.y = f2bf(__fmul_rn(a.y, b.y));
        r.z = f2bf(__fmul_rn(a.z, b.z));
        r.w = f2bf(__fmul_rn(a.w, b.w));
        ((ushort4*)P)[i] = r;
    } else {
        // ball query: one anchor per wave, ballot ordered extraction
        int lane = t & 63;
        int an = (blk - PRE_PREP - PRE_PROD) * 4 + (t >> 6);   // 0..8191
        int b = an >> 12;
        const float* nb = neighbor + (size_t)b * NN * 3;

        float ax = anchor[an * 3 + 0];
        float ay = anchor[an * 3 + 1];
        float az = anchor[an * 3 + 2];

        unsigned long long lmask = (lane == 63) ? 0xFFFFFFFFFFFFFFFFull >> 1
                                                : ((1ull << lane) - 1ull);
        int cnt = 0;
        int firstIdx = -1;
        int* myout = idx + (size_t)an * KNN;

        for (int chunk = 0; chunk < NN / 64 && cnt < KNN; ++chunk) {
            int j = chunk * 64 + lane;
            float dx = __fsub_rn(ax, nb[j * 3 + 0]);
            float dy = __fsub_rn(ay, nb[j * 3 + 1]);
            float dz = __fsub_rn(az, nb[j * 3 + 2]);
            float d2 = __fadd_rn(__fadd_rn(__fmul_rn(dx, dx), __fmul_rn(dy, dy)),
                                 __fmul_rn(dz, dz));
            bool hit = d2 < 1.0f;
            unsigned long long m = __ballot(hit);
            if (m) {
                int pos = cnt + __popcll(m & lmask);
                if (hit && pos < KNN) myout[pos] = j;
                if (firstIdx < 0) firstIdx = chunk * 64 + (__ffsll((long long)m) - 1);
                cnt += __popcll(m);
            }
        }
        if (cnt < KNN) {
            int f = (firstIdx < 0) ? 0 : firstIdx;
            if (lane >= cnt && lane < KNN) myout[lane] = f;
        }
    }
}

// ======================= GEMM0 (MFMA, LDS-free): gather + X@W0p^T, relu, stats =======================
__global__ __launch_bounds__(256) void k_gemm0(const float* __restrict__ anchor,
                                               const float* __restrict__ neighbor,
                                               const unsigned short* __restrict__ P,
                                               const int* __restrict__ idx,
                                               const short* __restrict__ W0p,
                                               unsigned short* __restrict__ y0,
                                               float* __restrict__ stats) {
    __shared__ float sred[CO * 2];
    int t = threadIdx.x;
    int rowBase = blockIdx.x * 128;
    sred[t] = 0.0f;          // t < 256 == CO*2
    __syncthreads();

    int lane = t & 63, w = t >> 6;
    int lm = lane & 15, g = lane >> 4;

    // ---- X fragments: 2 row-subtiles (i), 3 k-chunks ----
    bf16x8 xf[2][3];
#pragma unroll
    for (int i = 0; i < 2; ++i) {
        int r = rowBase + w * 32 + i * 16 + lm;
        int bn = r >> 4;            // b*4096+n
        int bb = r >> 16;
        int j = idx[r];
        const unsigned short* Prow = P + ((size_t)(bb << 12) + j) * CC;
        xf[i][0] = *(const bf16x8*)(Prow + g * 8);
        xf[i][1] = *(const bf16x8*)(Prow + 32 + g * 8);
        bf16x8 x2 = {0, 0, 0, 0, 0, 0, 0, 0};
        if (g == 0) {
            const float* nbr = neighbor + ((size_t)(bb << 12) + j) * 3;
            float dx = __fsub_rn(anchor[bn * 3 + 0], nbr[0]);
            float dy = __fsub_rn(anchor[bn * 3 + 1], nbr[1]);
            float dz = __fsub_rn(anchor[bn * 3 + 2], nbr[2]);
            x2[0] = (short)f2bf(dx);
            x2[1] = (short)f2bf(dy);
            x2[2] = (short)f2bf(dz);
        }
        xf[i][2] = x2;
    }

    f32x4 zero = {0.f, 0.f, 0.f, 0.f};
    f32x4 acc[2][8];
#pragma unroll
    for (int i = 0; i < 2; ++i)
#pragma unroll
        for (int c = 0; c < 8; ++c) acc[i][c] = zero;

#pragma unroll
    for (int kc = 0; kc < 3; ++kc) {
        int koff = kc * 32 + g * 8;
#pragma unroll
        for (int ct = 0; ct < 8; ++ct) {
            bf16x8 wf = *(const bf16x8*)&W0p[(ct * 16 + lm) * K0P + koff];
            acc[0][ct] = __builtin_amdgcn_mfma_f32_16x16x32_bf16(xf[0][kc], wf, acc[0][ct], 0, 0, 0);
            acc[1][ct] = __builtin_amdgcn_mfma_f32_16x16x32_bf16(xf[1][kc], wf, acc[1][ct], 0, 0, 0);
        }
    }

    // epilogue: relu, store bf16, stats (on relu'd values)
#pragma unroll
    for (int ct = 0; ct < 8; ++ct) {
        int o = lm + 16 * ct;
        float psum = 0.f, psq = 0.f;
#pragma unroll
        for (int i = 0; i < 2; ++i) {
#pragma unroll
            for (int rg = 0; rg < 4; ++rg) {
                float v = fmaxf(acc[i][ct][rg], 0.0f);
                int r = rowBase + w * 32 + i * 16 + g * 4 + rg;
                y0[(size_t)r * CO + o] = f2bf(v);
                psum += v; psq += v * v;
            }
        }
        psum += __shfl_xor(psum, 16); psq += __shfl_xor(psq, 16);
        psum += __shfl_xor(psum, 32); psq += __shfl_xor(psq, 32);
        if (lane < 16) {
            atomicAdd(&sred[o * 2 + 0], psum);
            atomicAdd(&sred[o * 2 + 1], psq);
        }
    }
    __syncthreads();
    int slot = blockIdx.x & (NSLOT - 1);
    atomicAdd(&stats[slot * CO * 2 + t], sred[t]);
}

// ======================= k_fold: BN0-fold into W1 -> W1s (bf16) + bias1 (f32) =======================
__global__ __launch_bounds__(256) void k_fold(const float* __restrict__ stats0,
                                              const float* __restrict__ gamma,
                                              const float* __restrict__ beta,
                                              const float* __restrict__ W1,
                                              short* __restrict__ W1s,
                                              float* __restrict__ bias1) {
    __shared__ float ssc[CO];
    __shared__ float ssh[CO];
    int t = threadIdx.x;
    if (t < 128) {
        float S = 0.0f, Q = 0.0f;
#pragma unroll
        for (int s = 0; s < NSLOT; ++s) {
            S += stats0[s * CO * 2 + t * 2 + 0];
            Q += stats0[s * CO * 2 + t * 2 + 1];
        }
        float inv = 1.0f / (float)ROWS;
        float mean = S * inv;
        float var = Q * inv - mean * mean;
        float sc = gamma[t] * rsqrtf(var + 1e-5f);
        ssc[t] = sc;
        ssh[t] = beta[t] - mean * sc;
    }
    __syncthreads();
    // W1s[o][k] = bf16(W1[o][k] * sc[k])
    for (int q = 0; q < 64; ++q) {
        int e = q * 256 + t;
        int k = e & 127;
        W1s[e] = (short)f2bf(W1[e] * ssc[k]);
    }
    // bias1[o] = sum_k sh[k] * W1[o][k]
    if (t < 128) {
        const float* wrow = W1 + t * 128;
        float s = 0.0f;
#pragma unroll
        for (int k = 0; k < 128; ++k) s = fmaf(ssh[k], wrow[k], s);
        bias1[t] = s;
    }
}

// ======================= GEMM1 (MFMA, BN0 folded, A prefetched) =======================
__global__ __launch_bounds__(256) void k_gemm1(const unsigned short* __restrict__ Xin,
                                               const short* __restrict__ W1s,
                                               const float* __restrict__ bias1,
                                               unsigned short* __restrict__ Hout,
                                               float* __restrict__ statsOut) {
    __shared__ alignas(16) short Wl[128 * WST];
    __shared__ float sbias[CO];
    __shared__ float sred[CO * 2];
    int t = threadIdx.x;
    int rowBase = blockIdx.x * 128;
    int lane = t & 63, w = t >> 6;
    int lm = lane & 15, g = lane >> 4;

    // prefetch all A fragments (raw bf16 rows feed MFMA directly — BN0 folded into W1s/bias1)
    bf16x8 afr[2][4];
#pragma unroll
    for (int i = 0; i < 2; ++i) {
        const unsigned short* xr = Xin + (size_t)(rowBase + w * 32 + i * 16 + lm) * CO;
#pragma unroll
        for (int kc = 0; kc < 4; ++kc)
            afr[i][kc] = *(const bf16x8*)(xr + kc * 32 + g * 8);
    }

    sred[t] = 0.0f;
    if (t < 128) sbias[t] = bias1[t];
    // stage W1s -> LDS (coalesced uint4)
#pragma unroll
    for (int q = 0; q < 8; ++q) {
        int e = (q * 256 + t) * 8;
        int o = e >> 7, k = e & 127;
        *(uint4*)&Wl[o * WST + k] = *(const uint4*)&W1s[e];
    }
    __syncthreads();

    f32x4 acc[2][8];
#pragma unroll
    for (int ct = 0; ct < 8; ++ct) {
        float b = sbias[lm + 16 * ct];
        f32x4 binit = {b, b, b, b};
        acc[0][ct] = binit;
        acc[1][ct] = binit;
    }

#pragma unroll
    for (int kc = 0; kc < 4; ++kc) {
        int k0 = kc * 32 + g * 8;
#pragma unroll
        for (int ct = 0; ct < 8; ++ct) {
            bf16x8 bfr = *(const bf16x8*)&Wl[(ct * 16 + lm) * WST + k0];
            acc[0][ct] = __builtin_amdgcn_mfma_f32_16x16x32_bf16(afr[0][kc], bfr, acc[0][ct], 0, 0, 0);
            acc[1][ct] = __builtin_amdgcn_mfma_f32_16x16x32_bf16(afr[1][kc], bfr, acc[1][ct], 0, 0, 0);
        }
    }

    // epilogue: store raw bf16 + stats on raw values
#pragma unroll
    for (int ct = 0; ct < 8; ++ct) {
        int o = lm + 16 * ct;
        float psum = 0.f, psq = 0.f;
#pragma unroll
        for (int i = 0; i < 2; ++i) {
#pragma unroll
            for (int rg = 0; rg < 4; ++rg) {
                float v = acc[i][ct][rg];
                int r = rowBase + w * 32 + i * 16 + g * 4 + rg;
                Hout[(size_t)r * CO + o] = f2bf(v);
                psum += v; psq += v * v;
            }
        }
        psum += __shfl_xor(psum, 16); psq += __shfl_xor(psq, 16);
        psum += __shfl_xor(psum, 32); psq += __shfl_xor(psq, 32);
        if (lane < 16) {
            atomicAdd(&sred[o * 2 + 0], psum);
            atomicAdd(&sred[o * 2 + 1], psq);
        }
    }
    __syncthreads();
    int slot = blockIdx.x & (NSLOT - 1);
    atomicAdd(&statsOut[slot * CO * 2 + t], sred[t]);
}

// ======================= GEMM2 (MFMA, fused BN1-finalize, relu transform, A prefetched) =======================
__global__ __launch_bounds__(256) void k_gemm2(const unsigned short* __restrict__ Xin,
                                               const short* __restrict__ Wp,
                                               const float* __restrict__ statsIn,
                                               const float* __restrict__ gamma,
                                               const float* __restrict__ beta,
                                               unsigned short* __restrict__ Hout,
                                               float* __restrict__ statsOut) {
    __shared__ alignas(16) short Wl[128 * WST];
    __shared__ float ssc[CO];
    __shared__ float ssh[CO];
    __shared__ float sred[CO * 2];
    int t = threadIdx.x;
    int rowBase = blockIdx.x * 128;
    int lane = t & 63, w = t >> 6;
    int lm = lane & 15, g = lane >> 4;

    // prefetch raw A rows (uint4 bits)
    uint4 xraw[2][4];
#pragma unroll
    for (int i = 0; i < 2; ++i) {
        const unsigned short* xr = Xin + (size_t)(rowBase + w * 32 + i * 16 + lm) * CO;
#pragma unroll
        for (int kc = 0; kc < 4; ++kc)
            xraw[i][kc] = *(const uint4*)(xr + kc * 32 + g * 8);
    }

    sred[t] = 0.0f;
    if (t < 128) {
        float S = 0.0f, Q = 0.0f;
#pragma unroll
        for (int s = 0; s < NSLOT; ++s) {
            S += statsIn[s * CO * 2 + t * 2 + 0];
            Q += statsIn[s * CO * 2 + t * 2 + 1];
        }
        float inv = 1.0f / (float)ROWS;
        float mean = S * inv;
        float var = Q * inv - mean * mean;
        float sc = gamma[t] * rsqrtf(var + 1e-5f);
        ssc[t] = sc;
        ssh[t] = beta[t] - mean * sc;
    }

    // stage W -> LDS (coalesced uint4)
#pragma unroll
    for (int q = 0; q < 8; ++q) {
        int e = (q * 256 + t) * 8;
        int o = e >> 7, k = e & 127;
        *(uint4*)&Wl[o * WST + k] = *(const uint4*)&Wp[e];
    }
    __syncthreads();

    f32x4 zero = {0.f, 0.f, 0.f, 0.f};
    f32x4 acc[2][8];
#pragma unroll
    for (int i = 0; i < 2; ++i)
#pragma unroll
        for (int c = 0; c < 8; ++c) acc[i][c] = zero;

#pragma unroll
    for (int kc = 0; kc < 4; ++kc) {
        int k0 = kc * 32 + g * 8;
        float scv[8], shv[8];
#pragma unroll
        for (int j = 0; j < 8; ++j) { scv[j] = ssc[k0 + j]; shv[j] = ssh[k0 + j]; }

        bf16x8 afr[2];
#pragma unroll
        for (int i = 0; i < 2; ++i) {
            U16B u; u.v = xraw[i][kc];
#pragma unroll
            for (int j = 0; j < 8; ++j) {
                float v = fmaxf(bf2f(u.us[j]) * scv[j] + shv[j], 0.0f);
                afr[i][j] = (short)f2bf(v);
            }
        }
#pragma unroll
        for (int ct = 0; ct < 8; ++ct) {
            bf16x8 bfr = *(const bf16x8*)&Wl[(ct * 16 + lm) * WST + k0];
            acc[0][ct] = __builtin_amdgcn_mfma_f32_16x16x32_bf16(afr[0], bfr, acc[0][ct], 0, 0, 0);
            acc[1][ct] = __builtin_amdgcn_mfma_f32_16x16x32_bf16(afr[1], bfr, acc[1][ct], 0, 0, 0);
        }
    }

    // epilogue: store raw bf16 + stats on raw values
#pragma unroll
    for (int ct = 0; ct < 8; ++ct) {
        int o = lm + 16 * ct;
        float psum = 0.f, psq = 0.f;
#pragma unroll
        for (int i = 0; i < 2; ++i) {
#pragma unroll
            for (int rg = 0; rg < 4; ++rg) {
                float v = acc[i][ct][rg];
                int r = rowBase + w * 32 + i * 16 + g * 4 + rg;
                Hout[(size_t)r * CO + o] = f2bf(v);
                psum += v; psq += v * v;
            }
        }
        psum += __shfl_xor(psum, 16); psq += __shfl_xor(psq, 16);
        psum += __shfl_xor(psum, 32); psq += __shfl_xor(psq, 32);
        if (lane < 16) {
            atomicAdd(&sred[o * 2 + 0], psum);
            atomicAdd(&sred[o * 2 + 1], psq);
        }
    }
    __syncthreads();
    int slot = blockIdx.x & (NSLOT - 1);
    atomicAdd(&statsOut[slot * CO * 2 + t], sred[t]);
}

// ---------------- output: fused BN2-finalize; one wave per point; max over K of relu(BN2(h2)) ----------------
__global__ __launch_bounds__(256) void k_out(const unsigned short* __restrict__ h2,
                                             const float* __restrict__ statsIn,
                                             const float* __restrict__ gamma,
                                             const float* __restrict__ beta,
                                             float* __restrict__ out) {
    __shared__ float ssc[CO];
    __shared__ float ssh[CO];
    int t = threadIdx.x;
    if (t < 128) {
        float S = 0.0f, Q = 0.0f;
#pragma unroll
        for (int s = 0; s < NSLOT; ++s) {
            S += statsIn[s * CO * 2 + t * 2 + 0];
            Q += statsIn[s * CO * 2 + t * 2 + 1];
        }
        float inv = 1.0f / (float)ROWS;
        float mean = S * inv;
        float var = Q * inv - mean * mean;
        float sc = gamma[t] * rsqrtf(var + 1e-5f);
        ssc[t] = sc;
        ssh[t] = beta[t] - mean * sc;
    }
    __syncthreads();

    int lane = t & 63, w = t >> 6;
    int bn = blockIdx.x * 4 + w;          // 0..8191
    int lm = lane & 15, g = lane >> 4;
    const unsigned short* base = h2 + (size_t)bn * KNN * CO;

    float scv[8], shv[8];
#pragma unroll
    for (int j = 0; j < 8; ++j) { scv[j] = ssc[lm * 8 + j]; shv[j] = ssh[lm * 8 + j]; }

    float m[8] = {0.f, 0.f, 0.f, 0.f, 0.f, 0.f, 0.f, 0.f};   // relu floor
#pragma unroll
    for (int rr = 0; rr < 4; ++rr) {
        U16B u;
        u.v = *(const uint4*)&base[(rr * 4 + g) * CO + lm * 8];
#pragma unroll
        for (int j = 0; j < 8; ++j) {
            float v = bf2f(u.us[j]) * scv[j] + shv[j];
            m[j] = fmaxf(m[j], v);
        }
    }
#pragma unroll
    for (int j = 0; j < 8; ++j) m[j] = fmaxf(m[j], __shfl_xor(m[j], 16));
#pragma unroll
    for (int j = 0; j < 8; ++j) m[j] = fmaxf(m[j], __shfl_xor(m[j], 32));
    if (g == 0) {
        float4 a = {m[0], m[1], m[2], m[3]};
        float4 b = {m[4], m[5], m[6], m[7]};
        *(float4*)&out[(size_t)bn * CO + lm * 8] = a;
        *(float4*)&out[(size_t)bn * CO + lm * 8 + 4] = b;
    }
}

extern "C" void kernel_launch(void* const* d_in, const int* in_sizes, int n_in,
                              void* d_out, int out_size, void* d_ws, size_t ws_size,
                              hipStream_t stream) {
    (void)in_sizes; (void)n_in; (void)out_size; (void)ws_size;
    const float* anchor = (const float*)d_in[0];
    const float* neighbor = (const float*)d_in[1];
    const float* nfeat = (const float*)d_in[2];
    const float* feat = (const float*)d_in[3];
    const float* W0 = (const float*)d_in[4];
    const float* g0 = (const float*)d_in[5];
    const float* b0 = (const float*)d_in[6];
    const float* W1 = (const float*)d_in[7];
    const float* g1 = (const float*)d_in[8];
    const float* b1 = (const float*)d_in[9];
    const float* W2 = (const float*)d_in[10];
    const float* g2 = (const float*)d_in[11];
    const float* b2 = (const float*)d_in[12];
    float* out = (float*)d_out;

    char* ws = (char*)d_ws;
    size_t o_idx = 0;                                   // 512 KB
    size_t o_P = o_idx + (size_t)ROWS * 4;              // bf16 P: 1 MB
    size_t o_stats = o_P + (size_t)BB * NN * CC * 2;    // 48 KB
    size_t o_W0p = o_stats + 3 * NSLOT * CO * 2 * 4;    // 24576 B
    size_t o_W2p = o_W0p + 128 * K0P * 2;               // 32768 B
    size_t o_W1s = o_W2p + 16384 * 2;                   // 32768 B
    size_t o_bias = o_W1s + 16384 * 2;                  // 512 B
    size_t o_bufA = (o_bias + 512 + 255) & ~(size_t)255;
    size_t o_bufB = o_bufA + (size_t)ROWS * CO * 2;     // bf16 buffers: 32 MB each

    int* idx = (int*)(ws + o_idx);
    unsigned short* P = (unsigned short*)(ws + o_P);
    float* stats0 = (float*)(ws + o_stats);
    float* stats1 = stats0 + NSLOT * CO * 2;
    float* stats2 = stats1 + NSLOT * CO * 2;
    short* W0p = (short*)(ws + o_W0p);
    short* W2p = (short*)(ws + o_W2p);
    short* W1s = (short*)(ws + o_W1s);
    float* bias1 = (float*)(ws + o_bias);
    unsigned short* bufA = (unsigned short*)(ws + o_bufA);   // y0, later h2
    unsigned short* bufB = (unsigned short*)(ws + o_bufB);   // h1

    k_pre<<<PRE_PREP + PRE_PROD + PRE_BALL, 256, 0, stream>>>(
        anchor, neighbor, feat, nfeat, W0, W2, W0p, W2p, stats0, idx, P);
    k_gemm0<<<ROWS / 128, 256, 0, stream>>>(anchor, neighbor, P, idx, W0p, bufA, stats0);
    k_fold<<<1, 256, 0, stream>>>(stats0, g0, b0, W1, W1s, bias1);
    k_gemm1<<<ROWS / 128, 256, 0, stream>>>(bufA, W1s, bias1, bufB, stats1);
    k_gemm2<<<ROWS / 128, 256, 0, stream>>>(bufB, W2p, stats1, g1, b1, bufA, stats2);
    k_out<<<BB * NN / 4, 256, 0, stream>>>(bufA, stats2, g2, b2, out);
}

// Round 10
// 106.768 us; speedup vs baseline: 7.8514x; 1.0542x over previous
//
#include <hip/hip_runtime.h>
#include <hip/hip_bf16.h>

#define BB 2
#define NN 4096
#define KNN 16
#define CC 64
#define CO 128
#define ROWS (BB*NN*KNN)   // 131072
#define K0P 96             // padded/permuted K for layer 0
#define NSLOT 16
#define WST 136            // 128 + 8 pad (bf16 elems)

// k_pre block ranges
#define PRE_PREP 112       // covers i < 28672
#define PRE_PROD 512       // 131072 float4 elems
#define PRE_BALL 2048      // 8192 anchors / 4 per block

typedef __attribute__((ext_vector_type(8))) short bf16x8;
typedef __attribute__((ext_vector_type(4))) float f32x4;

__device__ __forceinline__ float bf2f(unsigned short u) {
    return __uint_as_float(((unsigned)u) << 16);
}
__device__ __forceinline__ unsigned short f2bf(float f) {
    __hip_bfloat16 h = __float2bfloat16(f);
    return *reinterpret_cast<unsigned short*>(&h);
}

union U16B { uint4 v; unsigned short us[8]; };

// ======================= k_pre: stats-zero + W0 permute/cvt + W2 cvt + prod + ball =======================
__global__ __launch_bounds__(256) void k_pre(const float* __restrict__ anchor,
                                             const float* __restrict__ neighbor,
                                             const float* __restrict__ feat,
                                             const float* __restrict__ nfeat,
                                             const float* __restrict__ W0,
                                             const float* __restrict__ W2,
                                             short* __restrict__ W0p,
                                             short* __restrict__ W2p,
                                             float* __restrict__ stats,
                                             int* __restrict__ idx,
                                             unsigned short* __restrict__ P) {
    int blk = blockIdx.x;
    int t = threadIdx.x;
    if (blk < PRE_PREP) {
        int i = blk * 256 + t;
        if (i < 3 * NSLOT * CO * 2) stats[i] = 0.0f;          // 12288 floats
        if (i < 128 * K0P) {                                   // 12288
            int o = i / K0P, k = i - o * K0P;
            float v;
            if (k < 64)      v = W0[o * 67 + 3 + k];
            else if (k < 67) v = W0[o * 67 + (k - 64)];
            else             v = 0.0f;
            W0p[i] = (short)f2bf(v);
        } else if (i < 128 * K0P + 16384) {
            int e = i - 128 * K0P;
            W2p[e] = (short)f2bf(W2[e]);
        }
    } else if (blk < PRE_PREP + PRE_PROD) {
        int i = (blk - PRE_PREP) * 256 + t;                    // < 131072
        float4 a = ((const float4*)feat)[i];
        float4 b = ((const float4*)nfeat)[i];
        ushort4 r;
        r.x = f2bf(__fmul_rn(a.x, b.x));
        r.y = f2bf(__fmul_rn(a.y, b.y));
        r.z = f2bf(__fmul_rn(a.z, b.z));
        r.w = f2bf(__fmul_rn(a.w, b.w));
        ((ushort4*)P)[i] = r;
    } else {
        // ball query: one anchor per wave, ballot ordered extraction
        int lane = t & 63;
        int an = (blk - PRE_PREP - PRE_PROD) * 4 + (t >> 6);   // 0..8191
        int b = an >> 12;
        const float* nb = neighbor + (size_t)b * NN * 3;

        float ax = anchor[an * 3 + 0];
        float ay = anchor[an * 3 + 1];
        float az = anchor[an * 3 + 2];

        unsigned long long lmask = (lane == 63) ? 0xFFFFFFFFFFFFFFFFull >> 1
                                                : ((1ull << lane) - 1ull);
        int cnt = 0;
        int firstIdx = -1;
        int* myout = idx + (size_t)an * KNN;

        for (int chunk = 0; chunk < NN / 64 && cnt < KNN; ++chunk) {
            int j = chunk * 64 + lane;
            float dx = __fsub_rn(ax, nb[j * 3 + 0]);
            float dy = __fsub_rn(ay, nb[j * 3 + 1]);
            float dz = __fsub_rn(az, nb[j * 3 + 2]);
            float d2 = __fadd_rn(__fadd_rn(__fmul_rn(dx, dx), __fmul_rn(dy, dy)),
                                 __fmul_rn(dz, dz));
            bool hit = d2 < 1.0f;
            unsigned long long m = __ballot(hit);
            if (m) {
                int pos = cnt + __popcll(m & lmask);
                if (hit && pos < KNN) myout[pos] = j;
                if (firstIdx < 0) firstIdx = chunk * 64 + (__ffsll((long long)m) - 1);
                cnt += __popcll(m);
            }
        }
        if (cnt < KNN) {
            int f = (firstIdx < 0) ? 0 : firstIdx;
            if (lane >= cnt && lane < KNN) myout[lane] = f;
        }
    }
}

// ======================= GEMM0 (MFMA, LDS-free): gather + X@W0p^T, relu, stats =======================
__global__ __launch_bounds__(256) void k_gemm0(const float* __restrict__ anchor,
                                               const float* __restrict__ neighbor,
                                               const unsigned short* __restrict__ P,
                                               const int* __restrict__ idx,
                                               const short* __restrict__ W0p,
                                               unsigned short* __restrict__ y0,
                                               float* __restrict__ stats) {
    __shared__ float sred[CO * 2];
    int t = threadIdx.x;
    int rowBase = blockIdx.x * 128;
    sred[t] = 0.0f;          // t < 256 == CO*2
    __syncthreads();

    int lane = t & 63, w = t >> 6;
    int lm = lane & 15, g = lane >> 4;

    // ---- X fragments: 2 row-subtiles (i), 3 k-chunks ----
    bf16x8 xf[2][3];
#pragma unroll
    for (int i = 0; i < 2; ++i) {
        int r = rowBase + w * 32 + i * 16 + lm;
        int bn = r >> 4;            // b*4096+n
        int bb = r >> 16;
        int j = idx[r];
        const unsigned short* Prow = P + ((size_t)(bb << 12) + j) * CC;
        xf[i][0] = *(const bf16x8*)(Prow + g * 8);
        xf[i][1] = *(const bf16x8*)(Prow + 32 + g * 8);
        bf16x8 x2 = {0, 0, 0, 0, 0, 0, 0, 0};
        if (g == 0) {
            const float* nbr = neighbor + ((size_t)(bb << 12) + j) * 3;
            float dx = __fsub_rn(anchor[bn * 3 + 0], nbr[0]);
            float dy = __fsub_rn(anchor[bn * 3 + 1], nbr[1]);
            float dz = __fsub_rn(anchor[bn * 3 + 2], nbr[2]);
            x2[0] = (short)f2bf(dx);
            x2[1] = (short)f2bf(dy);
            x2[2] = (short)f2bf(dz);
        }
        xf[i][2] = x2;
    }

    f32x4 zero = {0.f, 0.f, 0.f, 0.f};
    f32x4 acc[2][8];
#pragma unroll
    for (int i = 0; i < 2; ++i)
#pragma unroll
        for (int c = 0; c < 8; ++c) acc[i][c] = zero;

#pragma unroll
    for (int kc = 0; kc < 3; ++kc) {
        int koff = kc * 32 + g * 8;
#pragma unroll
        for (int ct = 0; ct < 8; ++ct) {
            bf16x8 wf = *(const bf16x8*)&W0p[(ct * 16 + lm) * K0P + koff];
            acc[0][ct] = __builtin_amdgcn_mfma_f32_16x16x32_bf16(xf[0][kc], wf, acc[0][ct], 0, 0, 0);
            acc[1][ct] = __builtin_amdgcn_mfma_f32_16x16x32_bf16(xf[1][kc], wf, acc[1][ct], 0, 0, 0);
        }
    }

    // epilogue: relu, store bf16, stats (on relu'd values)
#pragma unroll
    for (int ct = 0; ct < 8; ++ct) {
        int o = lm + 16 * ct;
        float psum = 0.f, psq = 0.f;
#pragma unroll
        for (int i = 0; i < 2; ++i) {
#pragma unroll
            for (int rg = 0; rg < 4; ++rg) {
                float v = fmaxf(acc[i][ct][rg], 0.0f);
                int r = rowBase + w * 32 + i * 16 + g * 4 + rg;
                y0[(size_t)r * CO + o] = f2bf(v);
                psum += v; psq += v * v;
            }
        }
        psum += __shfl_xor(psum, 16); psq += __shfl_xor(psq, 16);
        psum += __shfl_xor(psum, 32); psq += __shfl_xor(psq, 32);
        if (lane < 16) {
            atomicAdd(&sred[o * 2 + 0], psum);
            atomicAdd(&sred[o * 2 + 1], psq);
        }
    }
    __syncthreads();
    int slot = blockIdx.x & (NSLOT - 1);
    atomicAdd(&stats[slot * CO * 2 + t], sred[t]);
}

// ======================= GEMM1 (MFMA, BN0-fold fused in prologue, A prefetched) =======================
// h1 = y0 @ (W1*sc0)^T + bias1, bias1[o] = sum_k sh0[k]*W1[o][k]
__global__ __launch_bounds__(256) void k_gemm1(const unsigned short* __restrict__ Xin,
                                               const float* __restrict__ W1,
                                               const float* __restrict__ stats0,
                                               const float* __restrict__ gamma,
                                               const float* __restrict__ beta,
                                               unsigned short* __restrict__ Hout,
                                               float* __restrict__ statsOut) {
    __shared__ alignas(16) short Wl[128 * WST];
    __shared__ float ssc[CO];
    __shared__ float ssh[CO];
    __shared__ float sbias[CO];
    __shared__ float sred[CO * 2];
    int t = threadIdx.x;
    int rowBase = blockIdx.x * 128;
    int lane = t & 63, w = t >> 6;
    int lm = lane & 15, g = lane >> 4;

    // prefetch all A fragments (raw bf16 rows feed MFMA directly)
    bf16x8 afr[2][4];
#pragma unroll
    for (int i = 0; i < 2; ++i) {
        const unsigned short* xr = Xin + (size_t)(rowBase + w * 32 + i * 16 + lm) * CO;
#pragma unroll
        for (int kc = 0; kc < 4; ++kc)
            afr[i][kc] = *(const bf16x8*)(xr + kc * 32 + g * 8);
    }

    sred[t] = 0.0f;
    if (t < 128) {
        float S = 0.0f, Q = 0.0f;
#pragma unroll
        for (int s = 0; s < NSLOT; ++s) {
            S += stats0[s * CO * 2 + t * 2 + 0];
            Q += stats0[s * CO * 2 + t * 2 + 1];
        }
        float inv = 1.0f / (float)ROWS;
        float mean = S * inv;
        float var = Q * inv - mean * mean;
        float sc = gamma[t] * rsqrtf(var + 1e-5f);
        ssc[t] = sc;
        ssh[t] = beta[t] - mean * sc;
    }
    __syncthreads();

    // stage W1 scaled by sc0 -> bf16 LDS
#pragma unroll
    for (int q = 0; q < 16; ++q) {
        int e4 = q * 256 + t;            // float4 index
        int o = e4 >> 5, kq = e4 & 31;
        float4 v = ((const float4*)W1)[e4];
        int k = kq * 4;
        ushort4 r;
        r.x = f2bf(v.x * ssc[k + 0]);
        r.y = f2bf(v.y * ssc[k + 1]);
        r.z = f2bf(v.z * ssc[k + 2]);
        r.w = f2bf(v.w * ssc[k + 3]);
        *(ushort4*)&Wl[o * WST + k] = r;
    }
    // bias1[o] = sum_k sh0[k]*W1[o][k]
    if (t < 128) {
        const float* wrow = W1 + t * 128;
        float s = 0.0f;
#pragma unroll
        for (int k = 0; k < 128; ++k) s = fmaf(ssh[k], wrow[k], s);
        sbias[t] = s;
    }
    __syncthreads();

    f32x4 acc[2][8];
#pragma unroll
    for (int ct = 0; ct < 8; ++ct) {
        float b = sbias[lm + 16 * ct];
        f32x4 binit = {b, b, b, b};
        acc[0][ct] = binit;
        acc[1][ct] = binit;
    }

#pragma unroll
    for (int kc = 0; kc < 4; ++kc) {
        int k0 = kc * 32 + g * 8;
#pragma unroll
        for (int ct = 0; ct < 8; ++ct) {
            bf16x8 bfr = *(const bf16x8*)&Wl[(ct * 16 + lm) * WST + k0];
            acc[0][ct] = __builtin_amdgcn_mfma_f32_16x16x32_bf16(afr[0][kc], bfr, acc[0][ct], 0, 0, 0);
            acc[1][ct] = __builtin_amdgcn_mfma_f32_16x16x32_bf16(afr[1][kc], bfr, acc[1][ct], 0, 0, 0);
        }
    }

    // epilogue: store raw bf16 + stats on raw values
#pragma unroll
    for (int ct = 0; ct < 8; ++ct) {
        int o = lm + 16 * ct;
        float psum = 0.f, psq = 0.f;
#pragma unroll
        for (int i = 0; i < 2; ++i) {
#pragma unroll
            for (int rg = 0; rg < 4; ++rg) {
                float v = acc[i][ct][rg];
                int r = rowBase + w * 32 + i * 16 + g * 4 + rg;
                Hout[(size_t)r * CO + o] = f2bf(v);
                psum += v; psq += v * v;
            }
        }
        psum += __shfl_xor(psum, 16); psq += __shfl_xor(psq, 16);
        psum += __shfl_xor(psum, 32); psq += __shfl_xor(psq, 32);
        if (lane < 16) {
            atomicAdd(&sred[o * 2 + 0], psum);
            atomicAdd(&sred[o * 2 + 1], psq);
        }
    }
    __syncthreads();
    int slot = blockIdx.x & (NSLOT - 1);
    atomicAdd(&statsOut[slot * CO * 2 + t], sred[t]);
}

// ======================= GEMM2 (MFMA, fused BN1-finalize + relu; K-max/min epilogue) =======================
// Writes per-point K-max and K-min of raw h2 (f32) instead of full h2; stats on raw h2.
__global__ __launch_bounds__(256) void k_gemm2(const unsigned short* __restrict__ Xin,
                                               const short* __restrict__ Wp,
                                               const float* __restrict__ statsIn,
                                               const float* __restrict__ gamma,
                                               const float* __restrict__ beta,
                                               float* __restrict__ maxh,
                                               float* __restrict__ minh,
                                               float* __restrict__ statsOut) {
    __shared__ alignas(16) short Wl[128 * WST];
    __shared__ float ssc[CO];
    __shared__ float ssh[CO];
    __shared__ float sred[CO * 2];
    int t = threadIdx.x;
    int rowBase = blockIdx.x * 128;
    int lane = t & 63, w = t >> 6;
    int lm = lane & 15, g = lane >> 4;

    // prefetch raw A rows (uint4 bits)
    uint4 xraw[2][4];
#pragma unroll
    for (int i = 0; i < 2; ++i) {
        const unsigned short* xr = Xin + (size_t)(rowBase + w * 32 + i * 16 + lm) * CO;
#pragma unroll
        for (int kc = 0; kc < 4; ++kc)
            xraw[i][kc] = *(const uint4*)(xr + kc * 32 + g * 8);
    }

    sred[t] = 0.0f;
    if (t < 128) {
        float S = 0.0f, Q = 0.0f;
#pragma unroll
        for (int s = 0; s < NSLOT; ++s) {
            S += statsIn[s * CO * 2 + t * 2 + 0];
            Q += statsIn[s * CO * 2 + t * 2 + 1];
        }
        float inv = 1.0f / (float)ROWS;
        float mean = S * inv;
        float var = Q * inv - mean * mean;
        float sc = gamma[t] * rsqrtf(var + 1e-5f);
        ssc[t] = sc;
        ssh[t] = beta[t] - mean * sc;
    }

    // stage W -> LDS (coalesced uint4)
#pragma unroll
    for (int q = 0; q < 8; ++q) {
        int e = (q * 256 + t) * 8;
        int o = e >> 7, k = e & 127;
        *(uint4*)&Wl[o * WST + k] = *(const uint4*)&Wp[e];
    }
    __syncthreads();

    f32x4 zero = {0.f, 0.f, 0.f, 0.f};
    f32x4 acc[2][8];
#pragma unroll
    for (int i = 0; i < 2; ++i)
#pragma unroll
        for (int c = 0; c < 8; ++c) acc[i][c] = zero;

#pragma unroll
    for (int kc = 0; kc < 4; ++kc) {
        int k0 = kc * 32 + g * 8;
        float scv[8], shv[8];
#pragma unroll
        for (int j = 0; j < 8; ++j) { scv[j] = ssc[k0 + j]; shv[j] = ssh[k0 + j]; }

        bf16x8 afr[2];
#pragma unroll
        for (int i = 0; i < 2; ++i) {
            U16B u; u.v = xraw[i][kc];
#pragma unroll
            for (int j = 0; j < 8; ++j) {
                float v = fmaxf(bf2f(u.us[j]) * scv[j] + shv[j], 0.0f);
                afr[i][j] = (short)f2bf(v);
            }
        }
#pragma unroll
        for (int ct = 0; ct < 8; ++ct) {
            bf16x8 bfr = *(const bf16x8*)&Wl[(ct * 16 + lm) * WST + k0];
            acc[0][ct] = __builtin_amdgcn_mfma_f32_16x16x32_bf16(afr[0], bfr, acc[0][ct], 0, 0, 0);
            acc[1][ct] = __builtin_amdgcn_mfma_f32_16x16x32_bf16(afr[1], bfr, acc[1][ct], 0, 0, 0);
        }
    }

    // epilogue: per-point K-max/min of raw h2 (f32) + stats on raw h2
#pragma unroll
    for (int ct = 0; ct < 8; ++ct) {
        int o = lm + 16 * ct;
        float psum = 0.f, psq = 0.f;
#pragma unroll
        for (int i = 0; i < 2; ++i) {
            float mx = acc[i][ct][0], mn = acc[i][ct][0];
#pragma unroll
            for (int rg = 0; rg < 4; ++rg) {
                float v = acc[i][ct][rg];
                psum += v; psq += v * v;
                mx = fmaxf(mx, v); mn = fminf(mn, v);
            }
            mx = fmaxf(mx, __shfl_xor(mx, 16)); mn = fminf(mn, __shfl_xor(mn, 16));
            mx = fmaxf(mx, __shfl_xor(mx, 32)); mn = fminf(mn, __shfl_xor(mn, 32));
            if (g == 0) {
                int pt = (rowBase >> 4) + w * 2 + i;   // point index 0..8191
                maxh[(size_t)pt * CO + o] = mx;
                minh[(size_t)pt * CO + o] = mn;
            }
        }
        psum += __shfl_xor(psum, 16); psq += __shfl_xor(psq, 16);
        psum += __shfl_xor(psum, 32); psq += __shfl_xor(psq, 32);
        if (lane < 16) {
            atomicAdd(&sred[o * 2 + 0], psum);
            atomicAdd(&sred[o * 2 + 1], psq);
        }
    }
    __syncthreads();
    int slot = blockIdx.x & (NSLOT - 1);
    atomicAdd(&statsOut[slot * CO * 2 + t], sred[t]);
}

// ---------------- output: BN2-finalize + monotone-select; out = relu(sc*(sc>=0?maxh:minh)+sh) ----------------
__global__ __launch_bounds__(256) void k_out(const float* __restrict__ maxh,
                                             const float* __restrict__ minh,
                                             const float* __restrict__ statsIn,
                                             const float* __restrict__ gamma,
                                             const float* __restrict__ beta,
                                             float* __restrict__ out) {
    __shared__ float ssc[CO];
    __shared__ float ssh[CO];
    int t = threadIdx.x;
    if (t < 128) {
        float S = 0.0f, Q = 0.0f;
#pragma unroll
        for (int s = 0; s < NSLOT; ++s) {
            S += statsIn[s * CO * 2 + t * 2 + 0];
            Q += statsIn[s * CO * 2 + t * 2 + 1];
        }
        float inv = 1.0f / (float)ROWS;
        float mean = S * inv;
        float var = Q * inv - mean * mean;
        float sc = gamma[t] * rsqrtf(var + 1e-5f);
        ssc[t] = sc;
        ssh[t] = beta[t] - mean * sc;
    }
    __syncthreads();

    int i4 = blockIdx.x * 256 + t;           // float4 index over 1M elems
    float4 mx = ((const float4*)maxh)[i4];
    float4 mn = ((const float4*)minh)[i4];
    int o = (i4 * 4) & 127;                   // 4 consecutive channels
    float4 r;
    {
        float sc = ssc[o + 0], sh = ssh[o + 0];
        r.x = fmaxf(sc * (sc >= 0.f ? mx.x : mn.x) + sh, 0.f);
        sc = ssc[o + 1]; sh = ssh[o + 1];
        r.y = fmaxf(sc * (sc >= 0.f ? mx.y : mn.y) + sh, 0.f);
        sc = ssc[o + 2]; sh = ssh[o + 2];
        r.z = fmaxf(sc * (sc >= 0.f ? mx.z : mn.z) + sh, 0.f);
        sc = ssc[o + 3]; sh = ssh[o + 3];
        r.w = fmaxf(sc * (sc >= 0.f ? mx.w : mn.w) + sh, 0.f);
    }
    ((float4*)out)[i4] = r;
}

extern "C" void kernel_launch(void* const* d_in, const int* in_sizes, int n_in,
                              void* d_out, int out_size, void* d_ws, size_t ws_size,
                              hipStream_t stream) {
    (void)in_sizes; (void)n_in; (void)out_size; (void)ws_size;
    const float* anchor = (const float*)d_in[0];
    const float* neighbor = (const float*)d_in[1];
    const float* nfeat = (const float*)d_in[2];
    const float* feat = (const float*)d_in[3];
    const float* W0 = (const float*)d_in[4];
    const float* g0 = (const float*)d_in[5];
    const float* b0 = (const float*)d_in[6];
    const float* W1 = (const float*)d_in[7];
    const float* g1 = (const float*)d_in[8];
    const float* b1 = (const float*)d_in[9];
    const float* W2 = (const float*)d_in[10];
    const float* g2 = (const float*)d_in[11];
    const float* b2 = (const float*)d_in[12];
    float* out = (float*)d_out;

    char* ws = (char*)d_ws;
    size_t o_idx = 0;                                   // 512 KB
    size_t o_P = o_idx + (size_t)ROWS * 4;              // bf16 P: 1 MB
    size_t o_stats = o_P + (size_t)BB * NN * CC * 2;    // 48 KB
    size_t o_W0p = o_stats + 3 * NSLOT * CO * 2 * 4;    // 24576 B
    size_t o_W2p = o_W0p + 128 * K0P * 2;               // 32768 B
    size_t o_maxh = (o_W2p + 16384 * 2 + 255) & ~(size_t)255;
    size_t o_minh = o_maxh + (size_t)BB * NN * CO * 4;  // 4 MB each
    size_t o_bufA = o_minh + (size_t)BB * NN * CO * 4;
    size_t o_bufB = o_bufA + (size_t)ROWS * CO * 2;     // bf16 buffers: 32 MB each

    int* idx = (int*)(ws + o_idx);
    unsigned short* P = (unsigned short*)(ws + o_P);
    float* stats0 = (float*)(ws + o_stats);
    float* stats1 = stats0 + NSLOT * CO * 2;
    float* stats2 = stats1 + NSLOT * CO * 2;
    short* W0p = (short*)(ws + o_W0p);
    short* W2p = (short*)(ws + o_W2p);
    float* maxh = (float*)(ws + o_maxh);
    float* minh = (float*)(ws + o_minh);
    unsigned short* bufA = (unsigned short*)(ws + o_bufA);   // y0
    unsigned short* bufB = (unsigned short*)(ws + o_bufB);   // h1

    k_pre<<<PRE_PREP + PRE_PROD + PRE_BALL, 256, 0, stream>>>(
        anchor, neighbor, feat, nfeat, W0, W2, W0p, W2p, stats0, idx, P);
    k_gemm0<<<ROWS / 128, 256, 0, stream>>>(anchor, neighbor, P, idx, W0p, bufA, stats0);
    k_gemm1<<<ROWS / 128, 256, 0, stream>>>(bufA, W1, stats0, g0, b0, bufB, stats1);
    k_gemm2<<<ROWS / 128, 256, 0, stream>>>(bufB, W2p, stats1, g1, b1, maxh, minh, stats2);
    k_out<<<BB * NN * CO / 1024, 256, 0, stream>>>(maxh, minh, stats2, g2, b2, out);
}